// Round 1
// baseline (1895.630 us; speedup 1.0000x reference)
//
#include <hip/hip_runtime.h>
#include <math.h>

// ---------------------------------------------------------------------------
// FraudGCN: GAT(128->4x64, concat) -> BN+ELU -> GAT(256->64) ||
//           SAGE(128->64) -> BN+ReLU -> SAGE(64->64)  -> concat -> MLP -> [N,2]
// Round 0: correctness-first f32 implementation.
//   - CSR-by-dst built once (deg/scan/scatter), reused by GAT (+implicit
//     self-loop) and SAGE (mean agg) layers.
//   - Wave-per-node segment softmax: online max/sum + butterfly reduce.
//   - Generic dual-input tiled SGEMM (64x64 tile, BK=32, 4x4/thread).
// ---------------------------------------------------------------------------

__device__ __forceinline__ float wred_max(float v) {
#pragma unroll
  for (int off = 1; off < 64; off <<= 1) v = fmaxf(v, __shfl_xor(v, off, 64));
  return v;
}
__device__ __forceinline__ float wred_sum(float v) {
#pragma unroll
  for (int off = 1; off < 64; off <<= 1) v += __shfl_xor(v, off, 64);
  return v;
}

// ---------------- CSR build ----------------
__global__ __launch_bounds__(256) void k_deg(const int* __restrict__ ei, int* __restrict__ deg, int E) {
  int e = blockIdx.x * blockDim.x + threadIdx.x;
  if (e < E) atomicAdd(&deg[ei[E + e]], 1);
}

__global__ __launch_bounds__(1024) void k_scan(const int* __restrict__ deg, int* __restrict__ row_ptr, int n) {
  __shared__ int sums[1024];
  int tid = threadIdx.x;
  int chunk = (n + 1023) / 1024;
  int lo = tid * chunk;
  int hi = min(lo + chunk, n);
  int s = 0;
  for (int i = lo; i < hi; ++i) s += deg[i];
  sums[tid] = s;
  __syncthreads();
  for (int off = 1; off < 1024; off <<= 1) {
    int v = (tid >= off) ? sums[tid - off] : 0;
    __syncthreads();
    sums[tid] += v;
    __syncthreads();
  }
  int run = sums[tid] - s;  // exclusive prefix
  for (int i = lo; i < hi; ++i) { row_ptr[i] = run; run += deg[i]; }
  if (tid == 1023) row_ptr[n] = sums[1023];
}

__global__ __launch_bounds__(256) void k_scatter(const int* __restrict__ ei, const int* __restrict__ row_ptr,
                                                 int* __restrict__ cursor, int* __restrict__ csr_src, int E) {
  int e = blockIdx.x * blockDim.x + threadIdx.x;
  if (e < E) {
    int d = ei[E + e];
    int pos = row_ptr[d] + atomicAdd(&cursor[d], 1);
    csr_src[pos] = ei[e];
  }
}

// ---------------- generic dual-input SGEMM ----------------
// C[Nrows,M] = act(A1[Nrows,K1]@W1[K1,M] + A2[Nrows,K2]@W2[K2,M] + bias)
// K's multiple of 32, M multiple of 64. act: 0=none, 1=relu.
__global__ __launch_bounds__(256) void k_gemm(const float* __restrict__ A1, int K1, const float* __restrict__ W1,
                                              const float* __restrict__ A2, int K2, const float* __restrict__ W2,
                                              const float* __restrict__ bias, float* __restrict__ C,
                                              int Nrows, int M, int act) {
  __shared__ float As[64][33];
  __shared__ float Ws[32][64];
  int row0 = blockIdx.x * 64;
  int col0 = blockIdx.y * 64;
  int tid = threadIdx.x;
  int tr = tid >> 4, tc = tid & 15;
  float acc[4][4] = {};
  for (int phase = 0; phase < 2; ++phase) {
    const float* A = phase ? A2 : A1;
    const float* W = phase ? W2 : W1;
    int K = phase ? K2 : K1;
    if (A == nullptr) continue;
    for (int k0 = 0; k0 < K; k0 += 32) {
      __syncthreads();
#pragma unroll
      for (int i = 0; i < 8; ++i) {  // stage A: 64x32
        int idx = tid + i * 256;
        int r = idx >> 5, kk = idx & 31;
        int gr = row0 + r;
        As[r][kk] = (gr < Nrows) ? A[(size_t)gr * K + k0 + kk] : 0.f;
      }
#pragma unroll
      for (int i = 0; i < 8; ++i) {  // stage W: 32x64
        int idx = tid + i * 256;
        int kk = idx >> 6, c = idx & 63;
        Ws[kk][c] = W[(size_t)(k0 + kk) * M + col0 + c];
      }
      __syncthreads();
#pragma unroll
      for (int kk = 0; kk < 32; ++kk) {
        float a[4], w[4];
#pragma unroll
        for (int i = 0; i < 4; ++i) a[i] = As[tr * 4 + i][kk];
#pragma unroll
        for (int j = 0; j < 4; ++j) w[j] = Ws[kk][tc * 4 + j];
#pragma unroll
        for (int i = 0; i < 4; ++i)
#pragma unroll
          for (int j = 0; j < 4; ++j) acc[i][j] += a[i] * w[j];
      }
    }
  }
#pragma unroll
  for (int i = 0; i < 4; ++i) {
    int gr = row0 + tr * 4 + i;
    if (gr >= Nrows) break;
#pragma unroll
    for (int j = 0; j < 4; ++j) {
      int gc = col0 + tc * 4 + j;
      float v = acc[i][j] + (bias ? bias[gc] : 0.f);
      if (act == 1) v = fmaxf(v, 0.f);
      C[(size_t)gr * M + gc] = v;
    }
  }
}

// ---------------- GAT attention prep: e_src/e_dst per (node, head) ----------
template <int H, int C>
__global__ __launch_bounds__(256) void k_attn_prep(const float* __restrict__ h, const float* __restrict__ a_src,
                                                   const float* __restrict__ a_dst, float* __restrict__ e_src,
                                                   float* __restrict__ e_dst, int n) {
  constexpr int HC = H * C;
  constexpr int VW = HC / 64;
  constexpr int GROUP = C / VW;  // lanes covering one head
  int wid = (blockIdx.x * blockDim.x + threadIdx.x) >> 6;
  int lane = threadIdx.x & 63;
  if (wid >= n) return;
  int c0 = lane * VW;
  float ps = 0.f, pd = 0.f;
#pragma unroll
  for (int j = 0; j < VW; ++j) {
    float hv = h[(size_t)wid * HC + c0 + j];
    ps += hv * a_src[c0 + j];
    pd += hv * a_dst[c0 + j];
  }
#pragma unroll
  for (int off = 1; off < GROUP; off <<= 1) {
    ps += __shfl_xor(ps, off, 64);
    pd += __shfl_xor(pd, off, 64);
  }
  if ((lane & (GROUP - 1)) == 0) {
    int hh = c0 / C;
    e_src[(size_t)wid * H + hh] = ps;
    e_dst[(size_t)wid * H + hh] = pd;
  }
}

// ---------------- GAT aggregate (wave per node, incl. self-loop) ------------
template <int H, int C>
__global__ __launch_bounds__(256) void k_gat_agg(const float* __restrict__ h, const float* __restrict__ e_src,
                                                 const float* __restrict__ e_dst, const int* __restrict__ row_ptr,
                                                 const int* __restrict__ csr, const float* __restrict__ bias,
                                                 float* __restrict__ out, int n) {
  constexpr int HC = H * C;
  constexpr int VW = HC / 64;
  int wid = (blockIdx.x * blockDim.x + threadIdx.x) >> 6;
  int lane = threadIdx.x & 63;
  if (wid >= n) return;
  int start = row_ptr[wid];
  int deg = row_ptr[wid + 1] - start;

  float edst[H];
  if constexpr (H == 4) {
    float4 t = *reinterpret_cast<const float4*>(e_dst + (size_t)wid * 4);
    edst[0] = t.x; edst[1] = t.y; edst[2] = t.z; edst[3] = t.w;
  } else {
    edst[0] = e_dst[wid];
  }

  // pass 1: online softmax stats per head, lanes stride edges (+1 self loop)
  float m[H], s[H];
#pragma unroll
  for (int hh = 0; hh < H; ++hh) { m[hh] = -INFINITY; s[hh] = 0.f; }
  for (int e = lane; e < deg + 1; e += 64) {
    int sn = (e < deg) ? csr[start + e] : wid;
    float es[H];
    if constexpr (H == 4) {
      float4 t = *reinterpret_cast<const float4*>(e_src + (size_t)sn * 4);
      es[0] = t.x; es[1] = t.y; es[2] = t.z; es[3] = t.w;
    } else {
      es[0] = e_src[sn];
    }
#pragma unroll
    for (int hh = 0; hh < H; ++hh) {
      float l = es[hh] + edst[hh];
      l = (l >= 0.f) ? l : 0.2f * l;
      if (l > m[hh]) {
        s[hh] = s[hh] * __expf(m[hh] - l) + 1.f;
        m[hh] = l;
      } else {
        s[hh] += __expf(l - m[hh]);
      }
    }
  }
#pragma unroll
  for (int hh = 0; hh < H; ++hh) {
    float M = wred_max(m[hh]);
    float sl = s[hh] * __expf(m[hh] - M);  // 0*0 = 0 for idle lanes
    sl = wred_sum(sl);
    m[hh] = M;
    s[hh] = sl;
  }

  // pass 2: weighted aggregation; lane covers channels [lane*VW, +VW)
  int c0 = lane * VW;
  int hl = c0 / C;
  float Mh = m[hl];
  float invS = 1.f / s[hl];
  float edl = edst[hl];
  float acc[VW] = {};
  for (int e = 0; e < deg + 1; ++e) {
    int sn = (e < deg) ? csr[start + e] : wid;
    float l = e_src[(size_t)sn * H + hl] + edl;
    l = (l >= 0.f) ? l : 0.2f * l;
    float alpha = __expf(l - Mh) * invS;
    if constexpr (VW == 4) {
      float4 hv = *(reinterpret_cast<const float4*>(h + (size_t)sn * HC) + lane);
      acc[0] += alpha * hv.x; acc[1] += alpha * hv.y;
      acc[2] += alpha * hv.z; acc[3] += alpha * hv.w;
    } else {
      acc[0] += alpha * h[(size_t)sn * HC + lane];
    }
  }
#pragma unroll
  for (int j = 0; j < VW; ++j) out[(size_t)wid * HC + c0 + j] = acc[j] + bias[c0 + j];
}

// ---------------- SAGE mean aggregation (wave per node) ----------------
template <int CH>
__global__ __launch_bounds__(256) void k_sage_agg(const float* __restrict__ x, const int* __restrict__ row_ptr,
                                                  const int* __restrict__ csr, float* __restrict__ agg, int n) {
  constexpr int VW = CH / 64;
  int wid = (blockIdx.x * blockDim.x + threadIdx.x) >> 6;
  int lane = threadIdx.x & 63;
  if (wid >= n) return;
  int start = row_ptr[wid];
  int deg = row_ptr[wid + 1] - start;
  float acc[VW] = {};
  for (int e = 0; e < deg; ++e) {
    int sn = csr[start + e];
    if constexpr (VW == 2) {
      float2 v = *(reinterpret_cast<const float2*>(x + (size_t)sn * CH) + lane);
      acc[0] += v.x; acc[1] += v.y;
    } else {
      acc[0] += x[(size_t)sn * CH + lane];
    }
  }
  float inv = 1.f / fmaxf((float)deg, 1.f);
#pragma unroll
  for (int j = 0; j < VW; ++j) agg[(size_t)wid * CH + lane * VW + j] = acc[j] * inv;
}

// ---------------- BatchNorm: stats then apply ----------------
template <int CH>
__global__ __launch_bounds__(256) void k_bn_stats(const float* __restrict__ x, float* __restrict__ stats, int n) {
  constexpr int RPB = 256 / CH;
  int tid = threadIdx.x;
  int c = tid % CH;
  int rsub = tid / CH;
  float s = 0.f, q = 0.f;
  for (int r = blockIdx.x * RPB + rsub; r < n; r += gridDim.x * RPB) {
    float v = x[(size_t)r * CH + c];
    s += v;
    q += v * v;
  }
  __shared__ float ls[256], lq[256];
  ls[tid] = s; lq[tid] = q;
  __syncthreads();
  if (tid < CH) {
#pragma unroll
    for (int i = 1; i < RPB; ++i) { s += ls[tid + i * CH]; q += lq[tid + i * CH]; }
    atomicAdd(&stats[c], s);
    atomicAdd(&stats[CH + c], q);
  }
}

// act: 1 = relu, 2 = elu
template <int CH>
__global__ __launch_bounds__(256) void k_bn_apply(float* __restrict__ x, const float* __restrict__ stats,
                                                  const float* __restrict__ gamma, const float* __restrict__ beta,
                                                  int n, int act) {
  float invn = 1.f / (float)n;
  size_t total = (size_t)n * CH;
  for (size_t idx = (size_t)blockIdx.x * blockDim.x + threadIdx.x; idx < total;
       idx += (size_t)gridDim.x * blockDim.x) {
    int c = (int)(idx % CH);
    float mu = stats[c] * invn;
    float var = stats[CH + c] * invn - mu * mu;
    float v = (x[idx] - mu) * rsqrtf(var + 1e-5f) * gamma[c] + beta[c];
    if (act == 1) v = fmaxf(v, 0.f);
    else v = (v > 0.f) ? v : (__expf(v) - 1.f);
    x[idx] = v;
  }
}

// ---------------- final head: out = fh[64] @ Wf2[64,2] + bf2 ----------------
__global__ __launch_bounds__(256) void k_head(const float* __restrict__ fh, const float* __restrict__ Wf2,
                                              const float* __restrict__ bf2, float* __restrict__ out, int n) {
  int wid = (blockIdx.x * blockDim.x + threadIdx.x) >> 6;
  int lane = threadIdx.x & 63;
  if (wid >= n) return;
  float hv = fh[(size_t)wid * 64 + lane];
  float p0 = hv * Wf2[lane * 2 + 0];
  float p1 = hv * Wf2[lane * 2 + 1];
  p0 = wred_sum(p0);
  p1 = wred_sum(p1);
  if (lane == 0) {
    out[(size_t)wid * 2 + 0] = p0 + bf2[0];
    out[(size_t)wid * 2 + 1] = p1 + bf2[1];
  }
}

// ---------------------------------------------------------------------------
extern "C" void kernel_launch(void* const* d_in, const int* in_sizes, int n_in,
                              void* d_out, int out_size, void* d_ws, size_t ws_size,
                              hipStream_t stream) {
  const float* x      = (const float*)d_in[0];
  const int*   ei     = (const int*)d_in[1];
  const float* W1g    = (const float*)d_in[2];
  const float* a_src1 = (const float*)d_in[3];
  const float* a_dst1 = (const float*)d_in[4];
  const float* b1g    = (const float*)d_in[5];
  const float* bn1g_g = (const float*)d_in[6];
  const float* bn1g_b = (const float*)d_in[7];
  const float* W2g    = (const float*)d_in[8];
  const float* a_src2 = (const float*)d_in[9];
  const float* a_dst2 = (const float*)d_in[10];
  const float* b2g    = (const float*)d_in[11];
  const float* Wl1    = (const float*)d_in[12];
  const float* bl1    = (const float*)d_in[13];
  const float* Wr1    = (const float*)d_in[14];
  const float* bn1s_g = (const float*)d_in[15];
  const float* bn1s_b = (const float*)d_in[16];
  const float* Wl2    = (const float*)d_in[17];
  const float* bl2    = (const float*)d_in[18];
  const float* Wr2    = (const float*)d_in[19];
  const float* Wf1    = (const float*)d_in[20];
  const float* bf1    = (const float*)d_in[21];
  const float* Wf2    = (const float*)d_in[22];
  const float* bf2    = (const float*)d_in[23];

  const int N = in_sizes[0] / 128;  // 100000
  const int E = in_sizes[1] / 2;    // 1600000

  char* ws = (char*)d_ws;
  size_t off = 0;
  auto alloc = [&](size_t bytes) -> void* {
    size_t o = (off + 255) & ~(size_t)255;
    off = o + bytes;
    return (void*)(ws + o);
  };

  float* h1    = (float*)alloc((size_t)N * 256 * 4);  // GAT1 features; later SAGE overlay
  float* gbuf  = (float*)alloc((size_t)N * 256 * 4);  // GAT1 out / g; later s2+fh overlay
  float* h2    = (float*)alloc((size_t)N * 64 * 4);
  float* g2    = (float*)alloc((size_t)N * 64 * 4);
  float* es1   = (float*)alloc((size_t)N * 4 * 4);
  float* ed1   = (float*)alloc((size_t)N * 4 * 4);
  float* es2   = (float*)alloc((size_t)N * 4);
  float* ed2   = (float*)alloc((size_t)N * 4);
  int* deg     = (int*)alloc((size_t)N * 4);
  int* cursor  = (int*)alloc((size_t)N * 4);
  int* row_ptr = (int*)alloc((size_t)(N + 1) * 4);
  int* csr     = (int*)alloc((size_t)E * 4);
  float* stats = (float*)alloc(2 * 256 * 4);
  // overlays (regions dead by the time they're reused):
  float* xagg  = h1;                        // [N,128] after GAT1 agg done
  float* s1    = h1 + (size_t)N * 128;      // [N,64]
  float* sagg2 = h1 + (size_t)N * 192;      // [N,64]
  float* s2    = gbuf;                      // [N,64] after GAT2 done
  float* fh    = gbuf + (size_t)N * 64;     // [N,64]

  const int tb = 256;
  const int nwb = (N + 3) / 4;  // wave-per-node: 4 waves/block

  // ---- CSR build ----
  hipMemsetAsync(deg, 0, (size_t)N * 4, stream);
  hipMemsetAsync(cursor, 0, (size_t)N * 4, stream);
  k_deg<<<(E + tb - 1) / tb, tb, 0, stream>>>(ei, deg, E);
  k_scan<<<1, 1024, 0, stream>>>(deg, row_ptr, N);
  k_scatter<<<(E + tb - 1) / tb, tb, 0, stream>>>(ei, row_ptr, cursor, csr, E);

  // ---- GAT layer 1 ----
  dim3 gemm1((N + 63) / 64, 4);  // M=256
  k_gemm<<<gemm1, 256, 0, stream>>>(x, 128, W1g, nullptr, 0, nullptr, nullptr, h1, N, 256, 0);
  k_attn_prep<4, 64><<<nwb, 256, 0, stream>>>(h1, a_src1, a_dst1, es1, ed1, N);
  k_gat_agg<4, 64><<<nwb, 256, 0, stream>>>(h1, es1, ed1, row_ptr, csr, b1g, gbuf, N);
  hipMemsetAsync(stats, 0, 2 * 256 * 4, stream);
  k_bn_stats<256><<<256, 256, 0, stream>>>(gbuf, stats, N);
  k_bn_apply<256><<<2048, 256, 0, stream>>>(gbuf, stats, bn1g_g, bn1g_b, N, 2);

  // ---- GAT layer 2 ----
  dim3 gemmM64((N + 63) / 64, 1);
  k_gemm<<<gemmM64, 256, 0, stream>>>(gbuf, 256, W2g, nullptr, 0, nullptr, nullptr, h2, N, 64, 0);
  k_attn_prep<1, 64><<<nwb, 256, 0, stream>>>(h2, a_src2, a_dst2, es2, ed2, N);
  k_gat_agg<1, 64><<<nwb, 256, 0, stream>>>(h2, es2, ed2, row_ptr, csr, b2g, g2, N);

  // ---- SAGE layer 1 (overlays h1 region; h1 dead now) ----
  k_sage_agg<128><<<nwb, 256, 0, stream>>>(x, row_ptr, csr, xagg, N);
  k_gemm<<<gemmM64, 256, 0, stream>>>(xagg, 128, Wl1, x, 128, Wr1, bl1, s1, N, 64, 0);
  hipMemsetAsync(stats, 0, 2 * 64 * 4, stream);
  k_bn_stats<64><<<256, 256, 0, stream>>>(s1, stats, N);
  k_bn_apply<64><<<2048, 256, 0, stream>>>(s1, stats, bn1s_g, bn1s_b, N, 1);

  // ---- SAGE layer 2 ----
  k_sage_agg<64><<<nwb, 256, 0, stream>>>(s1, row_ptr, csr, sagg2, N);
  k_gemm<<<gemmM64, 256, 0, stream>>>(sagg2, 64, Wl2, s1, 64, Wr2, bl2, s2, N, 64, 0);

  // ---- fusion MLP ----
  k_gemm<<<gemmM64, 256, 0, stream>>>(g2, 64, Wf1, s2, 64, Wf1 + 64 * 64, bf1, fh, N, 64, 1);
  k_head<<<nwb, 256, 0, stream>>>(fh, Wf2, bf2, (float*)d_out, N);
}

// Round 2
// 1339.787 us; speedup vs baseline: 1.4149x; 1.4149x over previous
//
#include <hip/hip_runtime.h>
#include <math.h>

// ---------------------------------------------------------------------------
// FraudGCN round 1: bf16 feature storage for all gathers + MFMA bf16 GEMMs.
// ---------------------------------------------------------------------------

typedef unsigned short u16;
typedef u16 us4 __attribute__((ext_vector_type(4)));
typedef u16 us2 __attribute__((ext_vector_type(2)));
typedef short s8v __attribute__((ext_vector_type(8)));
typedef float f4v __attribute__((ext_vector_type(4)));

__device__ __forceinline__ float b2f(u16 u) {
  union { unsigned int i; float f; } v; v.i = ((unsigned int)u) << 16; return v.f;
}
__device__ __forceinline__ u16 f2b(float f) {
  union { float f; unsigned int i; } v; v.f = f;
  unsigned int u = v.i;
  return (u16)((u + 0x7fffu + ((u >> 16) & 1u)) >> 16);
}

__device__ __forceinline__ float wred_max(float v) {
#pragma unroll
  for (int off = 1; off < 64; off <<= 1) v = fmaxf(v, __shfl_xor(v, off, 64));
  return v;
}
__device__ __forceinline__ float wred_sum(float v) {
#pragma unroll
  for (int off = 1; off < 64; off <<= 1) v += __shfl_xor(v, off, 64);
  return v;
}

// ---------------- casts ----------------
__global__ __launch_bounds__(256) void k_cast(const float* __restrict__ s, u16* __restrict__ d, int n4) {
  int i = blockIdx.x * blockDim.x + threadIdx.x;
  if (i < n4) {
    float4 v = *(reinterpret_cast<const float4*>(s) + i);
    us4 o = { f2b(v.x), f2b(v.y), f2b(v.z), f2b(v.w) };
    *(reinterpret_cast<us4*>(d) + i) = o;
  }
}

// Wt[c][k] = bf16(W[k][c]);  W is [K,M] row-major, Wt is [M,K]
__global__ __launch_bounds__(256) void k_wcast(const float* __restrict__ W, u16* __restrict__ Wt, int K, int M) {
  int idx = blockIdx.x * blockDim.x + threadIdx.x;
  if (idx >= K * M) return;
  int c = idx / K, k = idx - c * K;
  Wt[idx] = f2b(W[(size_t)k * M + c]);
}

// ---------------- CSR build ----------------
__global__ __launch_bounds__(256) void k_deg(const int* __restrict__ ei, int* __restrict__ deg, int E) {
  int e = blockIdx.x * blockDim.x + threadIdx.x;
  if (e < E) atomicAdd(&deg[ei[E + e]], 1);
}

__global__ __launch_bounds__(1024) void k_scan(const int* __restrict__ deg, int* __restrict__ row_ptr, int n) {
  __shared__ int sums[1024];
  int tid = threadIdx.x;
  int chunk = (n + 1023) / 1024;
  int lo = tid * chunk;
  int hi = min(lo + chunk, n);
  int s = 0;
  for (int i = lo; i < hi; ++i) s += deg[i];
  sums[tid] = s;
  __syncthreads();
  for (int off = 1; off < 1024; off <<= 1) {
    int v = (tid >= off) ? sums[tid - off] : 0;
    __syncthreads();
    sums[tid] += v;
    __syncthreads();
  }
  int run = sums[tid] - s;  // exclusive prefix
  for (int i = lo; i < hi; ++i) { row_ptr[i] = run; run += deg[i]; }
  if (tid == 1023) row_ptr[n] = sums[1023];
}

__global__ __launch_bounds__(256) void k_scatter(const int* __restrict__ ei, const int* __restrict__ row_ptr,
                                                 int* __restrict__ cursor, int* __restrict__ csr_src, int E) {
  int e = blockIdx.x * blockDim.x + threadIdx.x;
  if (e < E) {
    int d = ei[E + e];
    int pos = row_ptr[d] + atomicAdd(&cursor[d], 1);
    csr_src[pos] = ei[e];
  }
}

// ---------------- MFMA bf16 GEMM ----------------
// C[Nrows,M] = act(A1@W1t^T + A2@W2t^T + bias), A row-major [rows,K] bf16,
// Wt [M,K] bf16. K mult of 32, M mult of 64. Tile 64x64, 4 waves.
__global__ __launch_bounds__(256) void k_gemm_mfma(const u16* __restrict__ A1, int K1, const u16* __restrict__ W1t,
                                                   const u16* __restrict__ A2, int K2, const u16* __restrict__ W2t,
                                                   const float* __restrict__ bias, u16* __restrict__ C,
                                                   int Nrows, int M, int act) {
  __shared__ u16 As[64][40];
  __shared__ u16 Bs[64][40];
  int row0 = blockIdx.x * 64;
  int col0 = blockIdx.y * 64;
  int tid = threadIdx.x;
  int w = tid >> 6, lane = tid & 63;
  int lr = tid >> 2;               // staging row 0..63
  int lseg = (tid & 3) * 8;        // staging k-offset 0/8/16/24
  f4v acc[4];
#pragma unroll
  for (int n = 0; n < 4; ++n) acc[n] = (f4v){0.f, 0.f, 0.f, 0.f};

  int ar = (w << 4) + (lane & 15);
  int ak = (lane >> 4) << 3;

  for (int phase = 0; phase < 2; ++phase) {
    const u16* A = phase ? A2 : A1;
    const u16* Wt = phase ? W2t : W1t;
    int K = phase ? K2 : K1;
    if (A == nullptr) continue;
    for (int k0 = 0; k0 < K; k0 += 32) {
      __syncthreads();
      int gr = row0 + lr;
      s8v av = {};
      if (gr < Nrows) av = *reinterpret_cast<const s8v*>(A + (size_t)gr * K + k0 + lseg);
      *reinterpret_cast<s8v*>(&As[lr][lseg]) = av;
      s8v bv = *reinterpret_cast<const s8v*>(Wt + (size_t)(col0 + lr) * K + k0 + lseg);
      *reinterpret_cast<s8v*>(&Bs[lr][lseg]) = bv;
      __syncthreads();
      s8v af = *reinterpret_cast<const s8v*>(&As[ar][ak]);
#pragma unroll
      for (int n = 0; n < 4; ++n) {
        s8v bf = *reinterpret_cast<const s8v*>(&Bs[(n << 4) + (lane & 15)][ak]);
        acc[n] = __builtin_amdgcn_mfma_f32_16x16x32_bf16(af, bf, acc[n], 0, 0, 0);
      }
    }
  }

  int r0 = row0 + (w << 4) + ((lane >> 4) << 2);
  int cc = lane & 15;
#pragma unroll
  for (int n = 0; n < 4; ++n) {
    int gc = col0 + (n << 4) + cc;
    float bv = bias ? bias[gc] : 0.f;
#pragma unroll
    for (int j = 0; j < 4; ++j) {
      int gr = r0 + j;
      if (gr < Nrows) {
        float v = acc[n][j] + bv;
        if (act == 1) v = fmaxf(v, 0.f);
        C[(size_t)gr * M + gc] = f2b(v);
      }
    }
  }
}

// ---------------- GAT attention prep (bf16 h) ----------------
template <int H, int C>
__global__ __launch_bounds__(256) void k_attn_prep(const u16* __restrict__ h, const float* __restrict__ a_src,
                                                   const float* __restrict__ a_dst, float* __restrict__ e_src,
                                                   float* __restrict__ e_dst, int n) {
  constexpr int HC = H * C;
  constexpr int VW = HC / 64;
  constexpr int GROUP = C / VW;
  int wid = (blockIdx.x * blockDim.x + threadIdx.x) >> 6;
  int lane = threadIdx.x & 63;
  if (wid >= n) return;
  int c0 = lane * VW;
  float ps = 0.f, pd = 0.f;
  if constexpr (VW == 4) {
    us4 v = *reinterpret_cast<const us4*>(h + (size_t)wid * HC + c0);
#pragma unroll
    for (int j = 0; j < 4; ++j) {
      float hv = b2f(v[j]);
      ps += hv * a_src[c0 + j];
      pd += hv * a_dst[c0 + j];
    }
  } else {
    float hv = b2f(h[(size_t)wid * HC + c0]);
    ps = hv * a_src[c0];
    pd = hv * a_dst[c0];
  }
#pragma unroll
  for (int off = 1; off < GROUP; off <<= 1) {
    ps += __shfl_xor(ps, off, 64);
    pd += __shfl_xor(pd, off, 64);
  }
  if ((lane & (GROUP - 1)) == 0) {
    int hh = c0 / C;
    e_src[(size_t)wid * H + hh] = ps;
    e_dst[(size_t)wid * H + hh] = pd;
  }
}

// ---------------- GAT aggregate (bf16 h, wave per node, + self loop) --------
template <int H, int C>
__global__ __launch_bounds__(256) void k_gat_agg(const u16* __restrict__ h, const float* __restrict__ e_src,
                                                 const float* __restrict__ e_dst, const int* __restrict__ row_ptr,
                                                 const int* __restrict__ csr, const float* __restrict__ bias,
                                                 u16* __restrict__ out, int n) {
  constexpr int HC = H * C;
  constexpr int VW = HC / 64;
  int wid = (blockIdx.x * blockDim.x + threadIdx.x) >> 6;
  int lane = threadIdx.x & 63;
  if (wid >= n) return;
  int start = row_ptr[wid];
  int deg = row_ptr[wid + 1] - start;

  float edst[H];
  if constexpr (H == 4) {
    float4 t = *reinterpret_cast<const float4*>(e_dst + (size_t)wid * 4);
    edst[0] = t.x; edst[1] = t.y; edst[2] = t.z; edst[3] = t.w;
  } else {
    edst[0] = e_dst[wid];
  }

  float m[H], s[H];
#pragma unroll
  for (int hh = 0; hh < H; ++hh) { m[hh] = -INFINITY; s[hh] = 0.f; }
  for (int e = lane; e < deg + 1; e += 64) {
    int sn = (e < deg) ? csr[start + e] : wid;
    float es[H];
    if constexpr (H == 4) {
      float4 t = *reinterpret_cast<const float4*>(e_src + (size_t)sn * 4);
      es[0] = t.x; es[1] = t.y; es[2] = t.z; es[3] = t.w;
    } else {
      es[0] = e_src[sn];
    }
#pragma unroll
    for (int hh = 0; hh < H; ++hh) {
      float l = es[hh] + edst[hh];
      l = (l >= 0.f) ? l : 0.2f * l;
      if (l > m[hh]) {
        s[hh] = s[hh] * __expf(m[hh] - l) + 1.f;
        m[hh] = l;
      } else {
        s[hh] += __expf(l - m[hh]);
      }
    }
  }
#pragma unroll
  for (int hh = 0; hh < H; ++hh) {
    float M = wred_max(m[hh]);
    float sl = s[hh] * __expf(m[hh] - M);
    sl = wred_sum(sl);
    m[hh] = M;
    s[hh] = sl;
  }

  int c0 = lane * VW;
  int hl = c0 / C;
  float Mh = m[hl];
  float invS = 1.f / s[hl];
  float edl = edst[hl];
  float acc[VW] = {};
  for (int e = 0; e < deg + 1; ++e) {
    int sn = (e < deg) ? csr[start + e] : wid;
    float l = e_src[(size_t)sn * H + hl] + edl;
    l = (l >= 0.f) ? l : 0.2f * l;
    float alpha = __expf(l - Mh) * invS;
    if constexpr (VW == 4) {
      us4 hv = *(reinterpret_cast<const us4*>(h + (size_t)sn * HC) + lane);
#pragma unroll
      for (int j = 0; j < 4; ++j) acc[j] += alpha * b2f(hv[j]);
    } else {
      acc[0] += alpha * b2f(h[(size_t)sn * HC + lane]);
    }
  }
#pragma unroll
  for (int j = 0; j < VW; ++j) out[(size_t)wid * HC + c0 + j] = f2b(acc[j] + bias[c0 + j]);
}

// ---------------- SAGE mean aggregation (bf16 in/out) ----------------
template <int CH>
__global__ __launch_bounds__(256) void k_sage_agg(const u16* __restrict__ x, const int* __restrict__ row_ptr,
                                                  const int* __restrict__ csr, u16* __restrict__ agg, int n) {
  constexpr int VW = CH / 64;
  int wid = (blockIdx.x * blockDim.x + threadIdx.x) >> 6;
  int lane = threadIdx.x & 63;
  if (wid >= n) return;
  int start = row_ptr[wid];
  int deg = row_ptr[wid + 1] - start;
  float acc[VW] = {};
  for (int e = 0; e < deg; ++e) {
    int sn = csr[start + e];
    if constexpr (VW == 2) {
      us2 v = *(reinterpret_cast<const us2*>(x + (size_t)sn * CH) + lane);
      acc[0] += b2f(v[0]);
      acc[1] += b2f(v[1]);
    } else {
      acc[0] += b2f(x[(size_t)sn * CH + lane]);
    }
  }
  float inv = 1.f / fmaxf((float)deg, 1.f);
#pragma unroll
  for (int j = 0; j < VW; ++j) agg[(size_t)wid * CH + lane * VW + j] = f2b(acc[j] * inv);
}

// ---------------- BatchNorm: stats then apply (bf16 data) ----------------
template <int CH>
__global__ __launch_bounds__(256) void k_bn_stats(const u16* __restrict__ x, float* __restrict__ stats, int n) {
  constexpr int RPB = 256 / CH;
  int tid = threadIdx.x;
  int c = tid % CH;
  int rsub = tid / CH;
  float s = 0.f, q = 0.f;
  for (int r = blockIdx.x * RPB + rsub; r < n; r += gridDim.x * RPB) {
    float v = b2f(x[(size_t)r * CH + c]);
    s += v;
    q += v * v;
  }
  __shared__ float ls[256], lq[256];
  ls[tid] = s; lq[tid] = q;
  __syncthreads();
  if (tid < CH) {
#pragma unroll
    for (int i = 1; i < RPB; ++i) { s += ls[tid + i * CH]; q += lq[tid + i * CH]; }
    atomicAdd(&stats[c], s);
    atomicAdd(&stats[CH + c], q);
  }
}

// act: 1 = relu, 2 = elu
template <int CH>
__global__ __launch_bounds__(256) void k_bn_apply(u16* __restrict__ x, const float* __restrict__ stats,
                                                  const float* __restrict__ gamma, const float* __restrict__ beta,
                                                  int n, int act) {
  float invn = 1.f / (float)n;
  size_t total = (size_t)n * CH;
  for (size_t idx = (size_t)blockIdx.x * blockDim.x + threadIdx.x; idx < total;
       idx += (size_t)gridDim.x * blockDim.x) {
    int c = (int)(idx % CH);
    float mu = stats[c] * invn;
    float var = stats[CH + c] * invn - mu * mu;
    float v = (b2f(x[idx]) - mu) * rsqrtf(var + 1e-5f) * gamma[c] + beta[c];
    if (act == 1) v = fmaxf(v, 0.f);
    else v = (v > 0.f) ? v : (__expf(v) - 1.f);
    x[idx] = f2b(v);
  }
}

// ---------------- final head ----------------
__global__ __launch_bounds__(256) void k_head(const u16* __restrict__ fh, const float* __restrict__ Wf2,
                                              const float* __restrict__ bf2, float* __restrict__ out, int n) {
  int wid = (blockIdx.x * blockDim.x + threadIdx.x) >> 6;
  int lane = threadIdx.x & 63;
  if (wid >= n) return;
  float hv = b2f(fh[(size_t)wid * 64 + lane]);
  float p0 = hv * Wf2[lane * 2 + 0];
  float p1 = hv * Wf2[lane * 2 + 1];
  p0 = wred_sum(p0);
  p1 = wred_sum(p1);
  if (lane == 0) {
    out[(size_t)wid * 2 + 0] = p0 + bf2[0];
    out[(size_t)wid * 2 + 1] = p1 + bf2[1];
  }
}

// ---------------------------------------------------------------------------
extern "C" void kernel_launch(void* const* d_in, const int* in_sizes, int n_in,
                              void* d_out, int out_size, void* d_ws, size_t ws_size,
                              hipStream_t stream) {
  const float* x      = (const float*)d_in[0];
  const int*   ei     = (const int*)d_in[1];
  const float* W1g    = (const float*)d_in[2];
  const float* a_src1 = (const float*)d_in[3];
  const float* a_dst1 = (const float*)d_in[4];
  const float* b1g    = (const float*)d_in[5];
  const float* bn1g_g = (const float*)d_in[6];
  const float* bn1g_b = (const float*)d_in[7];
  const float* W2g    = (const float*)d_in[8];
  const float* a_src2 = (const float*)d_in[9];
  const float* a_dst2 = (const float*)d_in[10];
  const float* b2g    = (const float*)d_in[11];
  const float* Wl1    = (const float*)d_in[12];
  const float* bl1    = (const float*)d_in[13];
  const float* Wr1    = (const float*)d_in[14];
  const float* bn1s_g = (const float*)d_in[15];
  const float* bn1s_b = (const float*)d_in[16];
  const float* Wl2    = (const float*)d_in[17];
  const float* bl2    = (const float*)d_in[18];
  const float* Wr2    = (const float*)d_in[19];
  const float* Wf1    = (const float*)d_in[20];
  const float* bf1    = (const float*)d_in[21];
  const float* Wf2    = (const float*)d_in[22];
  const float* bf2    = (const float*)d_in[23];

  const int N = in_sizes[0] / 128;  // 100000
  const int E = in_sizes[1] / 2;    // 1600000

  char* ws = (char*)d_ws;
  size_t off = 0;
  auto alloc = [&](size_t bytes) -> void* {
    size_t o = (off + 255) & ~(size_t)255;
    off = o + bytes;
    return (void*)(ws + o);
  };

  u16* xb    = (u16*)alloc((size_t)N * 128 * 2);
  u16* h1b   = (u16*)alloc((size_t)N * 256 * 2);
  u16* gb    = (u16*)alloc((size_t)N * 256 * 2);
  u16* h2b   = (u16*)alloc((size_t)N * 64 * 2);
  u16* g2b   = (u16*)alloc((size_t)N * 64 * 2);
  u16* xaggb = (u16*)alloc((size_t)N * 128 * 2);
  u16* s1b   = (u16*)alloc((size_t)N * 64 * 2);
  u16* sagg2b= (u16*)alloc((size_t)N * 64 * 2);
  u16* s2b   = (u16*)alloc((size_t)N * 64 * 2);
  u16* fhb   = (u16*)alloc((size_t)N * 64 * 2);
  float* es1 = (float*)alloc((size_t)N * 4 * 4);
  float* ed1 = (float*)alloc((size_t)N * 4 * 4);
  float* es2 = (float*)alloc((size_t)N * 4);
  float* ed2 = (float*)alloc((size_t)N * 4);
  int* deg     = (int*)alloc((size_t)N * 4);
  int* cursor  = (int*)alloc((size_t)N * 4);
  int* row_ptr = (int*)alloc((size_t)(N + 1) * 4);
  int* csr     = (int*)alloc((size_t)E * 4);
  float* stats = (float*)alloc(2 * 256 * 4);
  u16* W1t  = (u16*)alloc(256 * 128 * 2);
  u16* W2t  = (u16*)alloc(64 * 256 * 2);
  u16* Wl1t = (u16*)alloc(64 * 128 * 2);
  u16* Wr1t = (u16*)alloc(64 * 128 * 2);
  u16* Wl2t = (u16*)alloc(64 * 64 * 2);
  u16* Wr2t = (u16*)alloc(64 * 64 * 2);
  u16* Wf1at= (u16*)alloc(64 * 64 * 2);
  u16* Wf1bt= (u16*)alloc(64 * 64 * 2);

  const int tb = 256;
  const int nwb = (N + 3) / 4;  // wave-per-node

  // ---- CSR build ----
  hipMemsetAsync(deg, 0, (size_t)N * 4, stream);
  hipMemsetAsync(cursor, 0, (size_t)N * 4, stream);
  k_deg<<<(E + tb - 1) / tb, tb, 0, stream>>>(ei, deg, E);
  k_scan<<<1, 1024, 0, stream>>>(deg, row_ptr, N);
  k_scatter<<<(E + tb - 1) / tb, tb, 0, stream>>>(ei, row_ptr, cursor, csr, E);

  // ---- casts ----
  k_cast<<<((N * 128 / 4) + tb - 1) / tb, tb, 0, stream>>>(x, xb, N * 128 / 4);
  k_wcast<<<(128 * 256 + tb - 1) / tb, tb, 0, stream>>>(W1g, W1t, 128, 256);
  k_wcast<<<(256 * 64 + tb - 1) / tb, tb, 0, stream>>>(W2g, W2t, 256, 64);
  k_wcast<<<(128 * 64 + tb - 1) / tb, tb, 0, stream>>>(Wl1, Wl1t, 128, 64);
  k_wcast<<<(128 * 64 + tb - 1) / tb, tb, 0, stream>>>(Wr1, Wr1t, 128, 64);
  k_wcast<<<(64 * 64 + tb - 1) / tb, tb, 0, stream>>>(Wl2, Wl2t, 64, 64);
  k_wcast<<<(64 * 64 + tb - 1) / tb, tb, 0, stream>>>(Wr2, Wr2t, 64, 64);
  k_wcast<<<(64 * 64 + tb - 1) / tb, tb, 0, stream>>>(Wf1, Wf1at, 64, 64);
  k_wcast<<<(64 * 64 + tb - 1) / tb, tb, 0, stream>>>(Wf1 + 64 * 64, Wf1bt, 64, 64);

  const int gx = (N + 63) / 64;

  // ---- GAT layer 1 ----
  dim3 gemm1(gx, 4);  // M=256
  k_gemm_mfma<<<gemm1, 256, 0, stream>>>(xb, 128, W1t, nullptr, 0, nullptr, nullptr, h1b, N, 256, 0);
  k_attn_prep<4, 64><<<nwb, 256, 0, stream>>>(h1b, a_src1, a_dst1, es1, ed1, N);
  k_gat_agg<4, 64><<<nwb, 256, 0, stream>>>(h1b, es1, ed1, row_ptr, csr, b1g, gb, N);
  hipMemsetAsync(stats, 0, 2 * 256 * 4, stream);
  k_bn_stats<256><<<256, 256, 0, stream>>>(gb, stats, N);
  k_bn_apply<256><<<2048, 256, 0, stream>>>(gb, stats, bn1g_g, bn1g_b, N, 2);

  // ---- GAT layer 2 ----
  dim3 gemmM64(gx, 1);
  k_gemm_mfma<<<gemmM64, 256, 0, stream>>>(gb, 256, W2t, nullptr, 0, nullptr, nullptr, h2b, N, 64, 0);
  k_attn_prep<1, 64><<<nwb, 256, 0, stream>>>(h2b, a_src2, a_dst2, es2, ed2, N);
  k_gat_agg<1, 64><<<nwb, 256, 0, stream>>>(h2b, es2, ed2, row_ptr, csr, b2g, g2b, N);

  // ---- SAGE layer 1 ----
  k_sage_agg<128><<<nwb, 256, 0, stream>>>(xb, row_ptr, csr, xaggb, N);
  k_gemm_mfma<<<gemmM64, 256, 0, stream>>>(xaggb, 128, Wl1t, xb, 128, Wr1t, bl1, s1b, N, 64, 0);
  hipMemsetAsync(stats, 0, 2 * 64 * 4, stream);
  k_bn_stats<64><<<256, 256, 0, stream>>>(s1b, stats, N);
  k_bn_apply<64><<<2048, 256, 0, stream>>>(s1b, stats, bn1s_g, bn1s_b, N, 1);

  // ---- SAGE layer 2 ----
  k_sage_agg<64><<<nwb, 256, 0, stream>>>(s1b, row_ptr, csr, sagg2b, N);
  k_gemm_mfma<<<gemmM64, 256, 0, stream>>>(sagg2b, 64, Wl2t, s1b, 64, Wr2t, bl2, s2b, N, 64, 0);

  // ---- fusion MLP ----
  k_gemm_mfma<<<gemmM64, 256, 0, stream>>>(g2b, 64, Wf1at, s2b, 64, Wf1bt, bf1, fhb, N, 64, 1);
  k_head<<<nwb, 256, 0, stream>>>(fhb, Wf2, bf2, (float*)d_out, N);
}

// Round 3
// 1061.699 us; speedup vs baseline: 1.7855x; 1.2619x over previous
//
#include <hip/hip_runtime.h>
#include <math.h>

// ---------------------------------------------------------------------------
// FraudGCN round 2: materialized edge alphas, unrolled gathers, SAGE1
// transform-before-aggregate, GEMM Cin fusion.
// ---------------------------------------------------------------------------

typedef unsigned short u16;
typedef u16 us4 __attribute__((ext_vector_type(4)));
typedef u16 us2 __attribute__((ext_vector_type(2)));
typedef short s8v __attribute__((ext_vector_type(8)));
typedef float f4v __attribute__((ext_vector_type(4)));

__device__ __forceinline__ float b2f(u16 u) {
  union { unsigned int i; float f; } v; v.i = ((unsigned int)u) << 16; return v.f;
}
__device__ __forceinline__ u16 f2b(float f) {
  union { float f; unsigned int i; } v; v.f = f;
  unsigned int u = v.i;
  return (u16)((u + 0x7fffu + ((u >> 16) & 1u)) >> 16);
}

__device__ __forceinline__ float wred_max(float v) {
#pragma unroll
  for (int off = 1; off < 64; off <<= 1) v = fmaxf(v, __shfl_xor(v, off, 64));
  return v;
}
__device__ __forceinline__ float wred_sum(float v) {
#pragma unroll
  for (int off = 1; off < 64; off <<= 1) v += __shfl_xor(v, off, 64);
  return v;
}

// ---------------- casts ----------------
__global__ __launch_bounds__(256) void k_cast(const float* __restrict__ s, u16* __restrict__ d, int n4) {
  int i = blockIdx.x * blockDim.x + threadIdx.x;
  if (i < n4) {
    float4 v = *(reinterpret_cast<const float4*>(s) + i);
    us4 o = { f2b(v.x), f2b(v.y), f2b(v.z), f2b(v.w) };
    *(reinterpret_cast<us4*>(d) + i) = o;
  }
}

// Wt[c][k] = bf16(W[k][c]);  W is [K,M] row-major, Wt is [M,K]
__global__ __launch_bounds__(256) void k_wcast(const float* __restrict__ W, u16* __restrict__ Wt, int K, int M) {
  int idx = blockIdx.x * blockDim.x + threadIdx.x;
  if (idx >= K * M) return;
  int c = idx / K, k = idx - c * K;
  Wt[idx] = f2b(W[(size_t)k * M + c]);
}

// ---------------- CSR build ----------------
__global__ __launch_bounds__(256) void k_deg(const int* __restrict__ ei, int* __restrict__ deg, int E) {
  int e = blockIdx.x * blockDim.x + threadIdx.x;
  if (e < E) atomicAdd(&deg[ei[E + e]], 1);
}

__global__ __launch_bounds__(1024) void k_scan(const int* __restrict__ deg, int* __restrict__ row_ptr, int n) {
  __shared__ int sums[1024];
  int tid = threadIdx.x;
  int chunk = (n + 1023) / 1024;
  int lo = tid * chunk;
  int hi = min(lo + chunk, n);
  int s = 0;
  for (int i = lo; i < hi; ++i) s += deg[i];
  sums[tid] = s;
  __syncthreads();
  for (int off = 1; off < 1024; off <<= 1) {
    int v = (tid >= off) ? sums[tid - off] : 0;
    __syncthreads();
    sums[tid] += v;
    __syncthreads();
  }
  int run = sums[tid] - s;  // exclusive prefix
  for (int i = lo; i < hi; ++i) { row_ptr[i] = run; run += deg[i]; }
  if (tid == 1023) row_ptr[n] = sums[1023];
}

__global__ __launch_bounds__(256) void k_scatter(const int* __restrict__ ei, const int* __restrict__ row_ptr,
                                                 int* __restrict__ cursor, int* __restrict__ csr_src, int E) {
  int e = blockIdx.x * blockDim.x + threadIdx.x;
  if (e < E) {
    int d = ei[E + e];
    int pos = row_ptr[d] + atomicAdd(&cursor[d], 1);
    csr_src[pos] = ei[e];
  }
}

// ---------------- MFMA bf16 GEMM ----------------
// C[Nrows,M] = act(A1@W1t^T + A2@W2t^T + Cin + bias). A row-major bf16,
// Wt [M,K] bf16. K mult of 32, M mult of 64. Tile 64x64, 4 waves.
__global__ __launch_bounds__(256) void k_gemm_mfma(const u16* __restrict__ A1, int K1, const u16* __restrict__ W1t,
                                                   const u16* __restrict__ A2, int K2, const u16* __restrict__ W2t,
                                                   const float* __restrict__ bias, const u16* __restrict__ Cin,
                                                   u16* __restrict__ C, int Nrows, int M, int act) {
  __shared__ u16 As[64][40];
  __shared__ u16 Bs[64][40];
  int row0 = blockIdx.x * 64;
  int col0 = blockIdx.y * 64;
  int tid = threadIdx.x;
  int w = tid >> 6, lane = tid & 63;
  int lr = tid >> 2;               // staging row 0..63
  int lseg = (tid & 3) * 8;        // staging k-offset 0/8/16/24
  f4v acc[4];
#pragma unroll
  for (int n = 0; n < 4; ++n) acc[n] = (f4v){0.f, 0.f, 0.f, 0.f};

  int ar = (w << 4) + (lane & 15);
  int ak = (lane >> 4) << 3;

  for (int phase = 0; phase < 2; ++phase) {
    const u16* A = phase ? A2 : A1;
    const u16* Wt = phase ? W2t : W1t;
    int K = phase ? K2 : K1;
    if (A == nullptr) continue;
    for (int k0 = 0; k0 < K; k0 += 32) {
      __syncthreads();
      int gr = row0 + lr;
      s8v av = {};
      if (gr < Nrows) av = *reinterpret_cast<const s8v*>(A + (size_t)gr * K + k0 + lseg);
      *reinterpret_cast<s8v*>(&As[lr][lseg]) = av;
      s8v bv = *reinterpret_cast<const s8v*>(Wt + (size_t)(col0 + lr) * K + k0 + lseg);
      *reinterpret_cast<s8v*>(&Bs[lr][lseg]) = bv;
      __syncthreads();
      s8v af = *reinterpret_cast<const s8v*>(&As[ar][ak]);
#pragma unroll
      for (int n = 0; n < 4; ++n) {
        s8v bf = *reinterpret_cast<const s8v*>(&Bs[(n << 4) + (lane & 15)][ak]);
        acc[n] = __builtin_amdgcn_mfma_f32_16x16x32_bf16(af, bf, acc[n], 0, 0, 0);
      }
    }
  }

  int r0 = row0 + (w << 4) + ((lane >> 4) << 2);
  int cc = lane & 15;
#pragma unroll
  for (int n = 0; n < 4; ++n) {
    int gc = col0 + (n << 4) + cc;
    float bv = bias ? bias[gc] : 0.f;
#pragma unroll
    for (int j = 0; j < 4; ++j) {
      int gr = r0 + j;
      if (gr < Nrows) {
        float v = acc[n][j] + bv;
        if (Cin) v += b2f(Cin[(size_t)gr * M + gc]);
        if (act == 1) v = fmaxf(v, 0.f);
        C[(size_t)gr * M + gc] = f2b(v);
      }
    }
  }
}

// ---------------- GAT attention prep (bf16 h) ----------------
template <int H, int C>
__global__ __launch_bounds__(256) void k_attn_prep(const u16* __restrict__ h, const float* __restrict__ a_src,
                                                   const float* __restrict__ a_dst, float* __restrict__ e_src,
                                                   float* __restrict__ e_dst, int n) {
  constexpr int HC = H * C;
  constexpr int VW = HC / 64;
  constexpr int GROUP = C / VW;
  int wid = (blockIdx.x * blockDim.x + threadIdx.x) >> 6;
  int lane = threadIdx.x & 63;
  if (wid >= n) return;
  int c0 = lane * VW;
  float ps = 0.f, pd = 0.f;
  if constexpr (VW == 4) {
    us4 v = *reinterpret_cast<const us4*>(h + (size_t)wid * HC + c0);
#pragma unroll
    for (int j = 0; j < 4; ++j) {
      float hv = b2f(v[j]);
      ps += hv * a_src[c0 + j];
      pd += hv * a_dst[c0 + j];
    }
  } else {
    float hv = b2f(h[(size_t)wid * HC + c0]);
    ps = hv * a_src[c0];
    pd = hv * a_dst[c0];
  }
#pragma unroll
  for (int off = 1; off < GROUP; off <<= 1) {
    ps += __shfl_xor(ps, off, 64);
    pd += __shfl_xor(pd, off, 64);
  }
  if ((lane & (GROUP - 1)) == 0) {
    int hh = c0 / C;
    e_src[(size_t)wid * H + hh] = ps;
    e_dst[(size_t)wid * H + hh] = pd;
  }
}

// ---------------- GAT softmax stats + alpha materialization ----------------
template <int H>
__global__ __launch_bounds__(256) void k_gat_stats(const float* __restrict__ es, const float* __restrict__ ed,
                                                   const int* __restrict__ row_ptr, const int* __restrict__ csr,
                                                   float* __restrict__ alphaE, float* __restrict__ alphaS, int n) {
  int wid = (blockIdx.x * blockDim.x + threadIdx.x) >> 6;
  int lane = threadIdx.x & 63;
  if (wid >= n) return;
  int start = row_ptr[wid];
  int deg = row_ptr[wid + 1] - start;

  float edst[H];
  if constexpr (H == 4) {
    float4 t = *reinterpret_cast<const float4*>(ed + (size_t)wid * 4);
    edst[0] = t.x; edst[1] = t.y; edst[2] = t.z; edst[3] = t.w;
  } else {
    edst[0] = ed[wid];
  }

  float m[H], s[H];
#pragma unroll
  for (int hh = 0; hh < H; ++hh) { m[hh] = -INFINITY; s[hh] = 0.f; }
  for (int e = lane; e < deg + 1; e += 64) {
    int sn = (e < deg) ? csr[start + e] : wid;
    float l[H];
    if constexpr (H == 4) {
      float4 t = *reinterpret_cast<const float4*>(es + (size_t)sn * 4);
      l[0] = t.x; l[1] = t.y; l[2] = t.z; l[3] = t.w;
    } else {
      l[0] = es[sn];
    }
#pragma unroll
    for (int hh = 0; hh < H; ++hh) {
      float v = l[hh] + edst[hh];
      v = (v >= 0.f) ? v : 0.2f * v;
      if (v > m[hh]) {
        s[hh] = s[hh] * __expf(m[hh] - v) + 1.f;
        m[hh] = v;
      } else {
        s[hh] += __expf(v - m[hh]);
      }
    }
  }
#pragma unroll
  for (int hh = 0; hh < H; ++hh) {
    float M = wred_max(m[hh]);
    float sl = s[hh] * __expf(m[hh] - M);
    sl = wred_sum(sl);
    m[hh] = M;
    s[hh] = 1.f / sl;
  }

  // write alphas
  for (int e = lane; e < deg + 1; e += 64) {
    int sn = (e < deg) ? csr[start + e] : wid;
    float a[H];
    if constexpr (H == 4) {
      float4 t = *reinterpret_cast<const float4*>(es + (size_t)sn * 4);
      a[0] = t.x; a[1] = t.y; a[2] = t.z; a[3] = t.w;
    } else {
      a[0] = es[sn];
    }
#pragma unroll
    for (int hh = 0; hh < H; ++hh) {
      float v = a[hh] + edst[hh];
      v = (v >= 0.f) ? v : 0.2f * v;
      a[hh] = __expf(v - m[hh]) * s[hh];
    }
    if constexpr (H == 4) {
      float4 o = { a[0], a[1], a[2], a[3] };
      if (e < deg) *reinterpret_cast<float4*>(alphaE + (size_t)(start + e) * 4) = o;
      else *reinterpret_cast<float4*>(alphaS + (size_t)wid * 4) = o;
    } else {
      if (e < deg) alphaE[start + e] = a[0];
      else alphaS[wid] = a[0];
    }
  }
}

// ---------------- GAT aggregate pass 2 (precomputed alphas) ----------------
template <int H, int C>
__global__ __launch_bounds__(256) void k_gat_agg2(const u16* __restrict__ h, const float* __restrict__ alphaE,
                                                  const float* __restrict__ alphaS, const int* __restrict__ row_ptr,
                                                  const int* __restrict__ csr, const float* __restrict__ bias,
                                                  u16* __restrict__ out, int n) {
  constexpr int HC = H * C;
  constexpr int VW = HC / 64;
  int wid = (blockIdx.x * blockDim.x + threadIdx.x) >> 6;
  int lane = threadIdx.x & 63;
  if (wid >= n) return;
  int start = row_ptr[wid];
  int deg = row_ptr[wid + 1] - start;
  int hl = (lane * VW) / C;

  float acc[VW];
  // self loop
  {
    float aS = alphaS[(size_t)wid * H + hl];
    if constexpr (VW == 4) {
      us4 hv = *(reinterpret_cast<const us4*>(h + (size_t)wid * HC) + lane);
#pragma unroll
      for (int j = 0; j < 4; ++j) acc[j] = aS * b2f(hv[j]);
    } else {
      acc[0] = aS * b2f(h[(size_t)wid * HC + lane]);
    }
  }

  int e = 0;
  for (; e + 4 <= deg; e += 4) {
    int sn[4];
    float al[4];
#pragma unroll
    for (int i = 0; i < 4; ++i) {
      sn[i] = csr[start + e + i];
      al[i] = alphaE[(size_t)(start + e + i) * H + hl];
    }
#pragma unroll
    for (int i = 0; i < 4; ++i) {
      if constexpr (VW == 4) {
        us4 hv = *(reinterpret_cast<const us4*>(h + (size_t)sn[i] * HC) + lane);
#pragma unroll
        for (int j = 0; j < 4; ++j) acc[j] += al[i] * b2f(hv[j]);
      } else {
        acc[0] += al[i] * b2f(h[(size_t)sn[i] * HC + lane]);
      }
    }
  }
  for (; e < deg; ++e) {
    int sn = csr[start + e];
    float al = alphaE[(size_t)(start + e) * H + hl];
    if constexpr (VW == 4) {
      us4 hv = *(reinterpret_cast<const us4*>(h + (size_t)sn * HC) + lane);
#pragma unroll
      for (int j = 0; j < 4; ++j) acc[j] += al * b2f(hv[j]);
    } else {
      acc[0] += al * b2f(h[(size_t)sn * HC + lane]);
    }
  }

  int c0 = lane * VW;
#pragma unroll
  for (int j = 0; j < VW; ++j) out[(size_t)wid * HC + c0 + j] = f2b(acc[j] + bias[c0 + j]);
}

// ---------------- SAGE mean aggregation (bf16 in/out, 64ch) ----------------
__global__ __launch_bounds__(256) void k_sage_agg64(const u16* __restrict__ x, const int* __restrict__ row_ptr,
                                                    const int* __restrict__ csr, u16* __restrict__ agg, int n) {
  int wid = (blockIdx.x * blockDim.x + threadIdx.x) >> 6;
  int lane = threadIdx.x & 63;
  if (wid >= n) return;
  int start = row_ptr[wid];
  int deg = row_ptr[wid + 1] - start;
  float acc = 0.f;
  int e = 0;
  for (; e + 4 <= deg; e += 4) {
    int sn[4];
#pragma unroll
    for (int i = 0; i < 4; ++i) sn[i] = csr[start + e + i];
#pragma unroll
    for (int i = 0; i < 4; ++i) acc += b2f(x[(size_t)sn[i] * 64 + lane]);
  }
  for (; e < deg; ++e) acc += b2f(x[(size_t)csr[start + e] * 64 + lane]);
  float inv = 1.f / fmaxf((float)deg, 1.f);
  agg[(size_t)wid * 64 + lane] = f2b(acc * inv);
}

// ---------------- BatchNorm: stats then apply (bf16 data) ----------------
template <int CH>
__global__ __launch_bounds__(256) void k_bn_stats(const u16* __restrict__ x, float* __restrict__ stats, int n) {
  constexpr int RPB = 256 / CH;
  int tid = threadIdx.x;
  int c = tid % CH;
  int rsub = tid / CH;
  float s = 0.f, q = 0.f;
  for (int r = blockIdx.x * RPB + rsub; r < n; r += gridDim.x * RPB) {
    float v = b2f(x[(size_t)r * CH + c]);
    s += v;
    q += v * v;
  }
  __shared__ float ls[256], lq[256];
  ls[tid] = s; lq[tid] = q;
  __syncthreads();
  if (tid < CH) {
#pragma unroll
    for (int i = 1; i < RPB; ++i) { s += ls[tid + i * CH]; q += lq[tid + i * CH]; }
    atomicAdd(&stats[c], s);
    atomicAdd(&stats[CH + c], q);
  }
}

// act: 1 = relu, 2 = elu
template <int CH>
__global__ __launch_bounds__(256) void k_bn_apply(u16* __restrict__ x, const float* __restrict__ stats,
                                                  const float* __restrict__ gamma, const float* __restrict__ beta,
                                                  int n, int act) {
  float invn = 1.f / (float)n;
  size_t total = (size_t)n * CH;
  for (size_t idx = (size_t)blockIdx.x * blockDim.x + threadIdx.x; idx < total;
       idx += (size_t)gridDim.x * blockDim.x) {
    int c = (int)(idx % CH);
    float mu = stats[c] * invn;
    float var = stats[CH + c] * invn - mu * mu;
    float v = (b2f(x[idx]) - mu) * rsqrtf(var + 1e-5f) * gamma[c] + beta[c];
    if (act == 1) v = fmaxf(v, 0.f);
    else v = (v > 0.f) ? v : (__expf(v) - 1.f);
    x[idx] = f2b(v);
  }
}

// ---------------- final head ----------------
__global__ __launch_bounds__(256) void k_head(const u16* __restrict__ fh, const float* __restrict__ Wf2,
                                              const float* __restrict__ bf2, float* __restrict__ out, int n) {
  int wid = (blockIdx.x * blockDim.x + threadIdx.x) >> 6;
  int lane = threadIdx.x & 63;
  if (wid >= n) return;
  float hv = b2f(fh[(size_t)wid * 64 + lane]);
  float p0 = hv * Wf2[lane * 2 + 0];
  float p1 = hv * Wf2[lane * 2 + 1];
  p0 = wred_sum(p0);
  p1 = wred_sum(p1);
  if (lane == 0) {
    out[(size_t)wid * 2 + 0] = p0 + bf2[0];
    out[(size_t)wid * 2 + 1] = p1 + bf2[1];
  }
}

// ---------------------------------------------------------------------------
extern "C" void kernel_launch(void* const* d_in, const int* in_sizes, int n_in,
                              void* d_out, int out_size, void* d_ws, size_t ws_size,
                              hipStream_t stream) {
  const float* x      = (const float*)d_in[0];
  const int*   ei     = (const int*)d_in[1];
  const float* W1g    = (const float*)d_in[2];
  const float* a_src1 = (const float*)d_in[3];
  const float* a_dst1 = (const float*)d_in[4];
  const float* b1g    = (const float*)d_in[5];
  const float* bn1g_g = (const float*)d_in[6];
  const float* bn1g_b = (const float*)d_in[7];
  const float* W2g    = (const float*)d_in[8];
  const float* a_src2 = (const float*)d_in[9];
  const float* a_dst2 = (const float*)d_in[10];
  const float* b2g    = (const float*)d_in[11];
  const float* Wl1    = (const float*)d_in[12];
  const float* bl1    = (const float*)d_in[13];
  const float* Wr1    = (const float*)d_in[14];
  const float* bn1s_g = (const float*)d_in[15];
  const float* bn1s_b = (const float*)d_in[16];
  const float* Wl2    = (const float*)d_in[17];
  const float* bl2    = (const float*)d_in[18];
  const float* Wr2    = (const float*)d_in[19];
  const float* Wf1    = (const float*)d_in[20];
  const float* bf1    = (const float*)d_in[21];
  const float* Wf2    = (const float*)d_in[22];
  const float* bf2    = (const float*)d_in[23];

  const int N = in_sizes[0] / 128;  // 100000
  const int E = in_sizes[1] / 2;    // 1600000

  char* ws = (char*)d_ws;
  size_t off = 0;
  auto alloc = [&](size_t bytes) -> void* {
    size_t o = (off + 255) & ~(size_t)255;
    off = o + bytes;
    return (void*)(ws + o);
  };

  u16* xb    = (u16*)alloc((size_t)N * 128 * 2);
  u16* h1b   = (u16*)alloc((size_t)N * 256 * 2);  // reused by SAGE after GAT1
  u16* gb    = (u16*)alloc((size_t)N * 256 * 2);  // reused by fh after GEMM2
  u16* h2b   = (u16*)alloc((size_t)N * 64 * 2);
  u16* g2b   = (u16*)alloc((size_t)N * 64 * 2);
  u16* s1b   = (u16*)alloc((size_t)N * 64 * 2);
  float* es1 = (float*)alloc((size_t)N * 4 * 4);
  float* ed1 = (float*)alloc((size_t)N * 4 * 4);
  float* es2 = (float*)alloc((size_t)N * 4);
  float* ed2 = (float*)alloc((size_t)N * 4);
  float* alphaE = (float*)alloc((size_t)E * 4 * 4);
  float* alphaS = (float*)alloc((size_t)N * 4 * 4);
  int* deg     = (int*)alloc((size_t)N * 4);
  int* cursor  = (int*)alloc((size_t)N * 4);
  int* row_ptr = (int*)alloc((size_t)(N + 1) * 4);
  int* csr     = (int*)alloc((size_t)E * 4);
  float* stats = (float*)alloc(2 * 256 * 4);
  u16* W1t  = (u16*)alloc(256 * 128 * 2);
  u16* W2t  = (u16*)alloc(64 * 256 * 2);
  u16* Wl1t = (u16*)alloc(64 * 128 * 2);
  u16* Wr1t = (u16*)alloc(64 * 128 * 2);
  u16* Wl2t = (u16*)alloc(64 * 64 * 2);
  u16* Wr2t = (u16*)alloc(64 * 64 * 2);
  u16* Wf1at= (u16*)alloc(64 * 64 * 2);
  u16* Wf1bt= (u16*)alloc(64 * 64 * 2);
  // overlays: SAGE buffers over h1b (dead after GAT1 agg); fh over gb (dead
  // after GEMM for h2).
  u16* xlb    = h1b;                       // [N,64]
  u16* saggb  = h1b + (size_t)N * 64;      // [N,64]
  u16* sagg2b = h1b + (size_t)N * 128;     // [N,64]
  u16* s2b    = h1b + (size_t)N * 192;     // [N,64]
  u16* fhb    = gb;                        // [N,64]

  const int tb = 256;
  const int nwb = (N + 3) / 4;  // wave-per-node

  // ---- CSR build ----
  hipMemsetAsync(deg, 0, (size_t)N * 4, stream);
  hipMemsetAsync(cursor, 0, (size_t)N * 4, stream);
  k_deg<<<(E + tb - 1) / tb, tb, 0, stream>>>(ei, deg, E);
  k_scan<<<1, 1024, 0, stream>>>(deg, row_ptr, N);
  k_scatter<<<(E + tb - 1) / tb, tb, 0, stream>>>(ei, row_ptr, cursor, csr, E);

  // ---- casts ----
  k_cast<<<((N * 128 / 4) + tb - 1) / tb, tb, 0, stream>>>(x, xb, N * 128 / 4);
  k_wcast<<<(128 * 256 + tb - 1) / tb, tb, 0, stream>>>(W1g, W1t, 128, 256);
  k_wcast<<<(256 * 64 + tb - 1) / tb, tb, 0, stream>>>(W2g, W2t, 256, 64);
  k_wcast<<<(128 * 64 + tb - 1) / tb, tb, 0, stream>>>(Wl1, Wl1t, 128, 64);
  k_wcast<<<(128 * 64 + tb - 1) / tb, tb, 0, stream>>>(Wr1, Wr1t, 128, 64);
  k_wcast<<<(64 * 64 + tb - 1) / tb, tb, 0, stream>>>(Wl2, Wl2t, 64, 64);
  k_wcast<<<(64 * 64 + tb - 1) / tb, tb, 0, stream>>>(Wr2, Wr2t, 64, 64);
  k_wcast<<<(64 * 64 + tb - 1) / tb, tb, 0, stream>>>(Wf1, Wf1at, 64, 64);
  k_wcast<<<(64 * 64 + tb - 1) / tb, tb, 0, stream>>>(Wf1 + 64 * 64, Wf1bt, 64, 64);

  const int gx = (N + 63) / 64;
  dim3 gemm1(gx, 4);    // M=256
  dim3 gemmM64(gx, 1);  // M=64

  // ---- GAT layer 1 ----
  k_gemm_mfma<<<gemm1, 256, 0, stream>>>(xb, 128, W1t, nullptr, 0, nullptr, nullptr, nullptr, h1b, N, 256, 0);
  k_attn_prep<4, 64><<<nwb, 256, 0, stream>>>(h1b, a_src1, a_dst1, es1, ed1, N);
  k_gat_stats<4><<<nwb, 256, 0, stream>>>(es1, ed1, row_ptr, csr, alphaE, alphaS, N);
  k_gat_agg2<4, 64><<<nwb, 256, 0, stream>>>(h1b, alphaE, alphaS, row_ptr, csr, b1g, gb, N);
  hipMemsetAsync(stats, 0, 2 * 256 * 4, stream);
  k_bn_stats<256><<<256, 256, 0, stream>>>(gb, stats, N);
  k_bn_apply<256><<<2048, 256, 0, stream>>>(gb, stats, bn1g_g, bn1g_b, N, 2);

  // ---- GAT layer 2 ----
  k_gemm_mfma<<<gemmM64, 256, 0, stream>>>(gb, 256, W2t, nullptr, 0, nullptr, nullptr, nullptr, h2b, N, 64, 0);
  k_attn_prep<1, 64><<<nwb, 256, 0, stream>>>(h2b, a_src2, a_dst2, es2, ed2, N);
  k_gat_stats<1><<<nwb, 256, 0, stream>>>(es2, ed2, row_ptr, csr, alphaE, alphaS, N);
  k_gat_agg2<1, 64><<<nwb, 256, 0, stream>>>(h2b, alphaE, alphaS, row_ptr, csr, b2g, g2b, N);

  // ---- SAGE layer 1: transform-before-aggregate ----
  k_gemm_mfma<<<gemmM64, 256, 0, stream>>>(xb, 128, Wl1t, nullptr, 0, nullptr, nullptr, nullptr, xlb, N, 64, 0);
  k_sage_agg64<<<nwb, 256, 0, stream>>>(xlb, row_ptr, csr, saggb, N);
  k_gemm_mfma<<<gemmM64, 256, 0, stream>>>(xb, 128, Wr1t, nullptr, 0, nullptr, bl1, saggb, s1b, N, 64, 0);
  hipMemsetAsync(stats, 0, 2 * 64 * 4, stream);
  k_bn_stats<64><<<256, 256, 0, stream>>>(s1b, stats, N);
  k_bn_apply<64><<<2048, 256, 0, stream>>>(s1b, stats, bn1s_g, bn1s_b, N, 1);

  // ---- SAGE layer 2 ----
  k_sage_agg64<<<nwb, 256, 0, stream>>>(s1b, row_ptr, csr, sagg2b, N);
  k_gemm_mfma<<<gemmM64, 256, 0, stream>>>(sagg2b, 64, Wl2t, s1b, 64, Wr2t, bl2, nullptr, s2b, N, 64, 0);

  // ---- fusion MLP ----
  k_gemm_mfma<<<gemmM64, 256, 0, stream>>>(g2b, 64, Wf1at, s2b, 64, Wf1bt, bf1, nullptr, fhb, N, 64, 1);
  k_head<<<nwb, 256, 0, stream>>>(fhb, Wf2, bf2, (float*)d_out, N);
}

// Round 4
// 887.941 us; speedup vs baseline: 2.1349x; 1.1957x over previous
//
#include <hip/hip_runtime.h>
#include <math.h>

// ---------------------------------------------------------------------------
// FraudGCN round 3: hierarchical CSR scan (was 160us single-block), fused
// weight casts. Rest unchanged from round 2.
// ---------------------------------------------------------------------------

typedef unsigned short u16;
typedef u16 us4 __attribute__((ext_vector_type(4)));
typedef u16 us2 __attribute__((ext_vector_type(2)));
typedef short s8v __attribute__((ext_vector_type(8)));
typedef float f4v __attribute__((ext_vector_type(4)));

__device__ __forceinline__ float b2f(u16 u) {
  union { unsigned int i; float f; } v; v.i = ((unsigned int)u) << 16; return v.f;
}
__device__ __forceinline__ u16 f2b(float f) {
  union { float f; unsigned int i; } v; v.f = f;
  unsigned int u = v.i;
  return (u16)((u + 0x7fffu + ((u >> 16) & 1u)) >> 16);
}

__device__ __forceinline__ float wred_max(float v) {
#pragma unroll
  for (int off = 1; off < 64; off <<= 1) v = fmaxf(v, __shfl_xor(v, off, 64));
  return v;
}
__device__ __forceinline__ float wred_sum(float v) {
#pragma unroll
  for (int off = 1; off < 64; off <<= 1) v += __shfl_xor(v, off, 64);
  return v;
}

// ---------------- casts ----------------
__global__ __launch_bounds__(256) void k_cast(const float* __restrict__ s, u16* __restrict__ d, int n4) {
  int i = blockIdx.x * blockDim.x + threadIdx.x;
  if (i < n4) {
    float4 v = *(reinterpret_cast<const float4*>(s) + i);
    us4 o = { f2b(v.x), f2b(v.y), f2b(v.z), f2b(v.w) };
    *(reinterpret_cast<us4*>(d) + i) = o;
  }
}

// Fused weight transpose+cast: Wt[c][k] = bf16(W[k][c]) for 8 weights.
struct WcastDesc { const float* W; u16* Wt; int K; int M; };
struct WcastAll { WcastDesc d[8]; };
__global__ __launch_bounds__(256) void k_wcast_all(WcastAll a) {
  WcastDesc de = a.d[blockIdx.y];
  int n = de.K * de.M;
  int idx = blockIdx.x * blockDim.x + threadIdx.x;
  if (idx >= n) return;
  int c = idx / de.K, k = idx - c * de.K;
  de.Wt[idx] = f2b(de.W[(size_t)k * de.M + c]);
}

// ---------------- CSR build ----------------
__global__ __launch_bounds__(256) void k_deg(const int* __restrict__ ei, int* __restrict__ deg, int E) {
  int e = blockIdx.x * blockDim.x + threadIdx.x;
  if (e < E) atomicAdd(&deg[ei[E + e]], 1);
}

// Hierarchical scan: (1) per-block local exclusive + block sums,
// (2) scan block sums (single block) + write grand total to row_ptr[n],
// (3) add block offsets.
__global__ __launch_bounds__(256) void k_scan1(const int* __restrict__ deg, int* __restrict__ row_ptr,
                                               int* __restrict__ bsum, int n) {
  __shared__ int sh[256];
  int tid = threadIdx.x;
  int i = blockIdx.x * 256 + tid;
  int v = (i < n) ? deg[i] : 0;
  sh[tid] = v;
  __syncthreads();
  for (int off = 1; off < 256; off <<= 1) {
    int t = (tid >= off) ? sh[tid - off] : 0;
    __syncthreads();
    sh[tid] += t;
    __syncthreads();
  }
  if (i < n) row_ptr[i] = sh[tid] - v;  // local exclusive
  if (tid == 255) bsum[blockIdx.x] = sh[255];
}

__global__ __launch_bounds__(1024) void k_scan2(int* __restrict__ bsum, int* __restrict__ total, int nb) {
  __shared__ int sh[1024];
  int tid = threadIdx.x;
  int v = (tid < nb) ? bsum[tid] : 0;
  sh[tid] = v;
  __syncthreads();
  for (int off = 1; off < 1024; off <<= 1) {
    int t = (tid >= off) ? sh[tid - off] : 0;
    __syncthreads();
    sh[tid] += t;
    __syncthreads();
  }
  if (tid < nb) bsum[tid] = sh[tid] - v;  // exclusive
  if (tid == 1023) *total = sh[1023];
}

__global__ __launch_bounds__(256) void k_scan3(int* __restrict__ row_ptr, const int* __restrict__ bsum, int n) {
  int i = blockIdx.x * 256 + threadIdx.x;
  if (i < n) row_ptr[i] += bsum[blockIdx.x];
}

__global__ __launch_bounds__(256) void k_scatter(const int* __restrict__ ei, const int* __restrict__ row_ptr,
                                                 int* __restrict__ cursor, int* __restrict__ csr_src, int E) {
  int e = blockIdx.x * blockDim.x + threadIdx.x;
  if (e < E) {
    int d = ei[E + e];
    int pos = row_ptr[d] + atomicAdd(&cursor[d], 1);
    csr_src[pos] = ei[e];
  }
}

// ---------------- MFMA bf16 GEMM ----------------
// C[Nrows,M] = act(A1@W1t^T + A2@W2t^T + Cin + bias). A row-major bf16,
// Wt [M,K] bf16. K mult of 32, M mult of 64. Tile 64x64, 4 waves.
__global__ __launch_bounds__(256) void k_gemm_mfma(const u16* __restrict__ A1, int K1, const u16* __restrict__ W1t,
                                                   const u16* __restrict__ A2, int K2, const u16* __restrict__ W2t,
                                                   const float* __restrict__ bias, const u16* __restrict__ Cin,
                                                   u16* __restrict__ C, int Nrows, int M, int act) {
  __shared__ u16 As[64][40];
  __shared__ u16 Bs[64][40];
  int row0 = blockIdx.x * 64;
  int col0 = blockIdx.y * 64;
  int tid = threadIdx.x;
  int w = tid >> 6, lane = tid & 63;
  int lr = tid >> 2;               // staging row 0..63
  int lseg = (tid & 3) * 8;        // staging k-offset 0/8/16/24
  f4v acc[4];
#pragma unroll
  for (int n = 0; n < 4; ++n) acc[n] = (f4v){0.f, 0.f, 0.f, 0.f};

  int ar = (w << 4) + (lane & 15);
  int ak = (lane >> 4) << 3;

  for (int phase = 0; phase < 2; ++phase) {
    const u16* A = phase ? A2 : A1;
    const u16* Wt = phase ? W2t : W1t;
    int K = phase ? K2 : K1;
    if (A == nullptr) continue;
    for (int k0 = 0; k0 < K; k0 += 32) {
      __syncthreads();
      int gr = row0 + lr;
      s8v av = {};
      if (gr < Nrows) av = *reinterpret_cast<const s8v*>(A + (size_t)gr * K + k0 + lseg);
      *reinterpret_cast<s8v*>(&As[lr][lseg]) = av;
      s8v bv = *reinterpret_cast<const s8v*>(Wt + (size_t)(col0 + lr) * K + k0 + lseg);
      *reinterpret_cast<s8v*>(&Bs[lr][lseg]) = bv;
      __syncthreads();
      s8v af = *reinterpret_cast<const s8v*>(&As[ar][ak]);
#pragma unroll
      for (int n = 0; n < 4; ++n) {
        s8v bf = *reinterpret_cast<const s8v*>(&Bs[(n << 4) + (lane & 15)][ak]);
        acc[n] = __builtin_amdgcn_mfma_f32_16x16x32_bf16(af, bf, acc[n], 0, 0, 0);
      }
    }
  }

  int r0 = row0 + (w << 4) + ((lane >> 4) << 2);
  int cc = lane & 15;
#pragma unroll
  for (int n = 0; n < 4; ++n) {
    int gc = col0 + (n << 4) + cc;
    float bv = bias ? bias[gc] : 0.f;
#pragma unroll
    for (int j = 0; j < 4; ++j) {
      int gr = r0 + j;
      if (gr < Nrows) {
        float v = acc[n][j] + bv;
        if (Cin) v += b2f(Cin[(size_t)gr * M + gc]);
        if (act == 1) v = fmaxf(v, 0.f);
        C[(size_t)gr * M + gc] = f2b(v);
      }
    }
  }
}

// ---------------- GAT attention prep (bf16 h) ----------------
template <int H, int C>
__global__ __launch_bounds__(256) void k_attn_prep(const u16* __restrict__ h, const float* __restrict__ a_src,
                                                   const float* __restrict__ a_dst, float* __restrict__ e_src,
                                                   float* __restrict__ e_dst, int n) {
  constexpr int HC = H * C;
  constexpr int VW = HC / 64;
  constexpr int GROUP = C / VW;
  int wid = (blockIdx.x * blockDim.x + threadIdx.x) >> 6;
  int lane = threadIdx.x & 63;
  if (wid >= n) return;
  int c0 = lane * VW;
  float ps = 0.f, pd = 0.f;
  if constexpr (VW == 4) {
    us4 v = *reinterpret_cast<const us4*>(h + (size_t)wid * HC + c0);
#pragma unroll
    for (int j = 0; j < 4; ++j) {
      float hv = b2f(v[j]);
      ps += hv * a_src[c0 + j];
      pd += hv * a_dst[c0 + j];
    }
  } else {
    float hv = b2f(h[(size_t)wid * HC + c0]);
    ps = hv * a_src[c0];
    pd = hv * a_dst[c0];
  }
#pragma unroll
  for (int off = 1; off < GROUP; off <<= 1) {
    ps += __shfl_xor(ps, off, 64);
    pd += __shfl_xor(pd, off, 64);
  }
  if ((lane & (GROUP - 1)) == 0) {
    int hh = c0 / C;
    e_src[(size_t)wid * H + hh] = ps;
    e_dst[(size_t)wid * H + hh] = pd;
  }
}

// ---------------- GAT softmax stats + alpha materialization ----------------
template <int H>
__global__ __launch_bounds__(256) void k_gat_stats(const float* __restrict__ es, const float* __restrict__ ed,
                                                   const int* __restrict__ row_ptr, const int* __restrict__ csr,
                                                   float* __restrict__ alphaE, float* __restrict__ alphaS, int n) {
  int wid = (blockIdx.x * blockDim.x + threadIdx.x) >> 6;
  int lane = threadIdx.x & 63;
  if (wid >= n) return;
  int start = row_ptr[wid];
  int deg = row_ptr[wid + 1] - start;

  float edst[H];
  if constexpr (H == 4) {
    float4 t = *reinterpret_cast<const float4*>(ed + (size_t)wid * 4);
    edst[0] = t.x; edst[1] = t.y; edst[2] = t.z; edst[3] = t.w;
  } else {
    edst[0] = ed[wid];
  }

  float m[H], s[H];
#pragma unroll
  for (int hh = 0; hh < H; ++hh) { m[hh] = -INFINITY; s[hh] = 0.f; }
  for (int e = lane; e < deg + 1; e += 64) {
    int sn = (e < deg) ? csr[start + e] : wid;
    float l[H];
    if constexpr (H == 4) {
      float4 t = *reinterpret_cast<const float4*>(es + (size_t)sn * 4);
      l[0] = t.x; l[1] = t.y; l[2] = t.z; l[3] = t.w;
    } else {
      l[0] = es[sn];
    }
#pragma unroll
    for (int hh = 0; hh < H; ++hh) {
      float v = l[hh] + edst[hh];
      v = (v >= 0.f) ? v : 0.2f * v;
      if (v > m[hh]) {
        s[hh] = s[hh] * __expf(m[hh] - v) + 1.f;
        m[hh] = v;
      } else {
        s[hh] += __expf(v - m[hh]);
      }
    }
  }
#pragma unroll
  for (int hh = 0; hh < H; ++hh) {
    float M = wred_max(m[hh]);
    float sl = s[hh] * __expf(m[hh] - M);
    sl = wred_sum(sl);
    m[hh] = M;
    s[hh] = 1.f / sl;
  }

  // write alphas
  for (int e = lane; e < deg + 1; e += 64) {
    int sn = (e < deg) ? csr[start + e] : wid;
    float a[H];
    if constexpr (H == 4) {
      float4 t = *reinterpret_cast<const float4*>(es + (size_t)sn * 4);
      a[0] = t.x; a[1] = t.y; a[2] = t.z; a[3] = t.w;
    } else {
      a[0] = es[sn];
    }
#pragma unroll
    for (int hh = 0; hh < H; ++hh) {
      float v = a[hh] + edst[hh];
      v = (v >= 0.f) ? v : 0.2f * v;
      a[hh] = __expf(v - m[hh]) * s[hh];
    }
    if constexpr (H == 4) {
      float4 o = { a[0], a[1], a[2], a[3] };
      if (e < deg) *reinterpret_cast<float4*>(alphaE + (size_t)(start + e) * 4) = o;
      else *reinterpret_cast<float4*>(alphaS + (size_t)wid * 4) = o;
    } else {
      if (e < deg) alphaE[start + e] = a[0];
      else alphaS[wid] = a[0];
    }
  }
}

// ---------------- GAT aggregate pass 2 (precomputed alphas) ----------------
template <int H, int C>
__global__ __launch_bounds__(256) void k_gat_agg2(const u16* __restrict__ h, const float* __restrict__ alphaE,
                                                  const float* __restrict__ alphaS, const int* __restrict__ row_ptr,
                                                  const int* __restrict__ csr, const float* __restrict__ bias,
                                                  u16* __restrict__ out, int n) {
  constexpr int HC = H * C;
  constexpr int VW = HC / 64;
  int wid = (blockIdx.x * blockDim.x + threadIdx.x) >> 6;
  int lane = threadIdx.x & 63;
  if (wid >= n) return;
  int start = row_ptr[wid];
  int deg = row_ptr[wid + 1] - start;
  int hl = (lane * VW) / C;

  float acc[VW];
  // self loop
  {
    float aS = alphaS[(size_t)wid * H + hl];
    if constexpr (VW == 4) {
      us4 hv = *(reinterpret_cast<const us4*>(h + (size_t)wid * HC) + lane);
#pragma unroll
      for (int j = 0; j < 4; ++j) acc[j] = aS * b2f(hv[j]);
    } else {
      acc[0] = aS * b2f(h[(size_t)wid * HC + lane]);
    }
  }

  int e = 0;
  for (; e + 4 <= deg; e += 4) {
    int sn[4];
    float al[4];
#pragma unroll
    for (int i = 0; i < 4; ++i) {
      sn[i] = csr[start + e + i];
      al[i] = alphaE[(size_t)(start + e + i) * H + hl];
    }
#pragma unroll
    for (int i = 0; i < 4; ++i) {
      if constexpr (VW == 4) {
        us4 hv = *(reinterpret_cast<const us4*>(h + (size_t)sn[i] * HC) + lane);
#pragma unroll
        for (int j = 0; j < 4; ++j) acc[j] += al[i] * b2f(hv[j]);
      } else {
        acc[0] += al[i] * b2f(h[(size_t)sn[i] * HC + lane]);
      }
    }
  }
  for (; e < deg; ++e) {
    int sn = csr[start + e];
    float al = alphaE[(size_t)(start + e) * H + hl];
    if constexpr (VW == 4) {
      us4 hv = *(reinterpret_cast<const us4*>(h + (size_t)sn * HC) + lane);
#pragma unroll
      for (int j = 0; j < 4; ++j) acc[j] += al * b2f(hv[j]);
    } else {
      acc[0] += al * b2f(h[(size_t)sn * HC + lane]);
    }
  }

  int c0 = lane * VW;
#pragma unroll
  for (int j = 0; j < VW; ++j) out[(size_t)wid * HC + c0 + j] = f2b(acc[j] + bias[c0 + j]);
}

// ---------------- SAGE mean aggregation (bf16 in/out, 64ch) ----------------
__global__ __launch_bounds__(256) void k_sage_agg64(const u16* __restrict__ x, const int* __restrict__ row_ptr,
                                                    const int* __restrict__ csr, u16* __restrict__ agg, int n) {
  int wid = (blockIdx.x * blockDim.x + threadIdx.x) >> 6;
  int lane = threadIdx.x & 63;
  if (wid >= n) return;
  int start = row_ptr[wid];
  int deg = row_ptr[wid + 1] - start;
  float acc = 0.f;
  int e = 0;
  for (; e + 4 <= deg; e += 4) {
    int sn[4];
#pragma unroll
    for (int i = 0; i < 4; ++i) sn[i] = csr[start + e + i];
#pragma unroll
    for (int i = 0; i < 4; ++i) acc += b2f(x[(size_t)sn[i] * 64 + lane]);
  }
  for (; e < deg; ++e) acc += b2f(x[(size_t)csr[start + e] * 64 + lane]);
  float inv = 1.f / fmaxf((float)deg, 1.f);
  agg[(size_t)wid * 64 + lane] = f2b(acc * inv);
}

// ---------------- BatchNorm: stats then apply (bf16 data) ----------------
template <int CH>
__global__ __launch_bounds__(256) void k_bn_stats(const u16* __restrict__ x, float* __restrict__ stats, int n) {
  constexpr int RPB = 256 / CH;
  int tid = threadIdx.x;
  int c = tid % CH;
  int rsub = tid / CH;
  float s = 0.f, q = 0.f;
  for (int r = blockIdx.x * RPB + rsub; r < n; r += gridDim.x * RPB) {
    float v = b2f(x[(size_t)r * CH + c]);
    s += v;
    q += v * v;
  }
  __shared__ float ls[256], lq[256];
  ls[tid] = s; lq[tid] = q;
  __syncthreads();
  if (tid < CH) {
#pragma unroll
    for (int i = 1; i < RPB; ++i) { s += ls[tid + i * CH]; q += lq[tid + i * CH]; }
    atomicAdd(&stats[c], s);
    atomicAdd(&stats[CH + c], q);
  }
}

// act: 1 = relu, 2 = elu
template <int CH>
__global__ __launch_bounds__(256) void k_bn_apply(u16* __restrict__ x, const float* __restrict__ stats,
                                                  const float* __restrict__ gamma, const float* __restrict__ beta,
                                                  int n, int act) {
  float invn = 1.f / (float)n;
  size_t total = (size_t)n * CH;
  for (size_t idx = (size_t)blockIdx.x * blockDim.x + threadIdx.x; idx < total;
       idx += (size_t)gridDim.x * blockDim.x) {
    int c = (int)(idx % CH);
    float mu = stats[c] * invn;
    float var = stats[CH + c] * invn - mu * mu;
    float v = (b2f(x[idx]) - mu) * rsqrtf(var + 1e-5f) * gamma[c] + beta[c];
    if (act == 1) v = fmaxf(v, 0.f);
    else v = (v > 0.f) ? v : (__expf(v) - 1.f);
    x[idx] = f2b(v);
  }
}

// ---------------- final head ----------------
__global__ __launch_bounds__(256) void k_head(const u16* __restrict__ fh, const float* __restrict__ Wf2,
                                              const float* __restrict__ bf2, float* __restrict__ out, int n) {
  int wid = (blockIdx.x * blockDim.x + threadIdx.x) >> 6;
  int lane = threadIdx.x & 63;
  if (wid >= n) return;
  float hv = b2f(fh[(size_t)wid * 64 + lane]);
  float p0 = hv * Wf2[lane * 2 + 0];
  float p1 = hv * Wf2[lane * 2 + 1];
  p0 = wred_sum(p0);
  p1 = wred_sum(p1);
  if (lane == 0) {
    out[(size_t)wid * 2 + 0] = p0 + bf2[0];
    out[(size_t)wid * 2 + 1] = p1 + bf2[1];
  }
}

// ---------------------------------------------------------------------------
extern "C" void kernel_launch(void* const* d_in, const int* in_sizes, int n_in,
                              void* d_out, int out_size, void* d_ws, size_t ws_size,
                              hipStream_t stream) {
  const float* x      = (const float*)d_in[0];
  const int*   ei     = (const int*)d_in[1];
  const float* W1g    = (const float*)d_in[2];
  const float* a_src1 = (const float*)d_in[3];
  const float* a_dst1 = (const float*)d_in[4];
  const float* b1g    = (const float*)d_in[5];
  const float* bn1g_g = (const float*)d_in[6];
  const float* bn1g_b = (const float*)d_in[7];
  const float* W2g    = (const float*)d_in[8];
  const float* a_src2 = (const float*)d_in[9];
  const float* a_dst2 = (const float*)d_in[10];
  const float* b2g    = (const float*)d_in[11];
  const float* Wl1    = (const float*)d_in[12];
  const float* bl1    = (const float*)d_in[13];
  const float* Wr1    = (const float*)d_in[14];
  const float* bn1s_g = (const float*)d_in[15];
  const float* bn1s_b = (const float*)d_in[16];
  const float* Wl2    = (const float*)d_in[17];
  const float* bl2    = (const float*)d_in[18];
  const float* Wr2    = (const float*)d_in[19];
  const float* Wf1    = (const float*)d_in[20];
  const float* bf1    = (const float*)d_in[21];
  const float* Wf2    = (const float*)d_in[22];
  const float* bf2    = (const float*)d_in[23];

  const int N = in_sizes[0] / 128;  // 100000
  const int E = in_sizes[1] / 2;    // 1600000

  char* ws = (char*)d_ws;
  size_t off = 0;
  auto alloc = [&](size_t bytes) -> void* {
    size_t o = (off + 255) & ~(size_t)255;
    off = o + bytes;
    return (void*)(ws + o);
  };

  u16* xb    = (u16*)alloc((size_t)N * 128 * 2);
  u16* h1b   = (u16*)alloc((size_t)N * 256 * 2);  // reused by SAGE after GAT1
  u16* gb    = (u16*)alloc((size_t)N * 256 * 2);  // reused by fh after GEMM2
  u16* h2b   = (u16*)alloc((size_t)N * 64 * 2);
  u16* g2b   = (u16*)alloc((size_t)N * 64 * 2);
  u16* s1b   = (u16*)alloc((size_t)N * 64 * 2);
  float* es1 = (float*)alloc((size_t)N * 4 * 4);
  float* ed1 = (float*)alloc((size_t)N * 4 * 4);
  float* es2 = (float*)alloc((size_t)N * 4);
  float* ed2 = (float*)alloc((size_t)N * 4);
  float* alphaE = (float*)alloc((size_t)E * 4 * 4);
  float* alphaS = (float*)alloc((size_t)N * 4 * 4);
  int* deg     = (int*)alloc((size_t)N * 2 * 4);   // deg + cursor contiguous
  int* cursor  = deg + N;
  int* row_ptr = (int*)alloc((size_t)(N + 1) * 4);
  int* bsum    = (int*)alloc(1024 * 4);
  int* csr     = (int*)alloc((size_t)E * 4);
  float* stats = (float*)alloc(2 * 256 * 4);
  u16* W1t  = (u16*)alloc(256 * 128 * 2);
  u16* W2t  = (u16*)alloc(64 * 256 * 2);
  u16* Wl1t = (u16*)alloc(64 * 128 * 2);
  u16* Wr1t = (u16*)alloc(64 * 128 * 2);
  u16* Wl2t = (u16*)alloc(64 * 64 * 2);
  u16* Wr2t = (u16*)alloc(64 * 64 * 2);
  u16* Wf1at= (u16*)alloc(64 * 64 * 2);
  u16* Wf1bt= (u16*)alloc(64 * 64 * 2);
  // overlays: SAGE buffers over h1b (dead after GAT1 agg); fh over gb (dead
  // after GEMM for h2).
  u16* xlb    = h1b;                       // [N,64]
  u16* saggb  = h1b + (size_t)N * 64;      // [N,64]
  u16* sagg2b = h1b + (size_t)N * 128;     // [N,64]
  u16* s2b    = h1b + (size_t)N * 192;     // [N,64]
  u16* fhb    = gb;                        // [N,64]

  const int tb = 256;
  const int nwb = (N + 3) / 4;       // wave-per-node
  const int nsb = (N + 255) / 256;   // scan blocks (391 for N=100k)

  // ---- CSR build ----
  hipMemsetAsync(deg, 0, (size_t)N * 2 * 4, stream);
  k_deg<<<(E + tb - 1) / tb, tb, 0, stream>>>(ei, deg, E);
  k_scan1<<<nsb, 256, 0, stream>>>(deg, row_ptr, bsum, N);
  k_scan2<<<1, 1024, 0, stream>>>(bsum, row_ptr + N, nsb);
  k_scan3<<<nsb, 256, 0, stream>>>(row_ptr, bsum, N);
  k_scatter<<<(E + tb - 1) / tb, tb, 0, stream>>>(ei, row_ptr, cursor, csr, E);

  // ---- casts ----
  k_cast<<<((N * 128 / 4) + tb - 1) / tb, tb, 0, stream>>>(x, xb, N * 128 / 4);
  WcastAll wa;
  wa.d[0] = { W1g, W1t, 128, 256 };
  wa.d[1] = { W2g, W2t, 256, 64 };
  wa.d[2] = { Wl1, Wl1t, 128, 64 };
  wa.d[3] = { Wr1, Wr1t, 128, 64 };
  wa.d[4] = { Wl2, Wl2t, 64, 64 };
  wa.d[5] = { Wr2, Wr2t, 64, 64 };
  wa.d[6] = { Wf1, Wf1at, 64, 64 };
  wa.d[7] = { Wf1 + 64 * 64, Wf1bt, 64, 64 };
  dim3 wgrid((128 * 256 + tb - 1) / tb, 8);
  k_wcast_all<<<wgrid, tb, 0, stream>>>(wa);

  const int gx = (N + 63) / 64;
  dim3 gemm1(gx, 4);    // M=256
  dim3 gemmM64(gx, 1);  // M=64

  // ---- GAT layer 1 ----
  k_gemm_mfma<<<gemm1, 256, 0, stream>>>(xb, 128, W1t, nullptr, 0, nullptr, nullptr, nullptr, h1b, N, 256, 0);
  k_attn_prep<4, 64><<<nwb, 256, 0, stream>>>(h1b, a_src1, a_dst1, es1, ed1, N);
  k_gat_stats<4><<<nwb, 256, 0, stream>>>(es1, ed1, row_ptr, csr, alphaE, alphaS, N);
  k_gat_agg2<4, 64><<<nwb, 256, 0, stream>>>(h1b, alphaE, alphaS, row_ptr, csr, b1g, gb, N);
  hipMemsetAsync(stats, 0, 2 * 256 * 4, stream);
  k_bn_stats<256><<<256, 256, 0, stream>>>(gb, stats, N);
  k_bn_apply<256><<<2048, 256, 0, stream>>>(gb, stats, bn1g_g, bn1g_b, N, 2);

  // ---- GAT layer 2 ----
  k_gemm_mfma<<<gemmM64, 256, 0, stream>>>(gb, 256, W2t, nullptr, 0, nullptr, nullptr, nullptr, h2b, N, 64, 0);
  k_attn_prep<1, 64><<<nwb, 256, 0, stream>>>(h2b, a_src2, a_dst2, es2, ed2, N);
  k_gat_stats<1><<<nwb, 256, 0, stream>>>(es2, ed2, row_ptr, csr, alphaE, alphaS, N);
  k_gat_agg2<1, 64><<<nwb, 256, 0, stream>>>(h2b, alphaE, alphaS, row_ptr, csr, b2g, g2b, N);

  // ---- SAGE layer 1: transform-before-aggregate ----
  k_gemm_mfma<<<gemmM64, 256, 0, stream>>>(xb, 128, Wl1t, nullptr, 0, nullptr, nullptr, nullptr, xlb, N, 64, 0);
  k_sage_agg64<<<nwb, 256, 0, stream>>>(xlb, row_ptr, csr, saggb, N);
  k_gemm_mfma<<<gemmM64, 256, 0, stream>>>(xb, 128, Wr1t, nullptr, 0, nullptr, bl1, saggb, s1b, N, 64, 0);
  hipMemsetAsync(stats, 0, 2 * 64 * 4, stream);
  k_bn_stats<64><<<256, 256, 0, stream>>>(s1b, stats, N);
  k_bn_apply<64><<<2048, 256, 0, stream>>>(s1b, stats, bn1s_g, bn1s_b, N, 1);

  // ---- SAGE layer 2 ----
  k_sage_agg64<<<nwb, 256, 0, stream>>>(s1b, row_ptr, csr, sagg2b, N);
  k_gemm_mfma<<<gemmM64, 256, 0, stream>>>(sagg2b, 64, Wl2t, s1b, 64, Wr2t, bl2, nullptr, s2b, N, 64, 0);

  // ---- fusion MLP ----
  k_gemm_mfma<<<gemmM64, 256, 0, stream>>>(g2b, 64, Wf1at, s2b, 64, Wf1bt, bf1, nullptr, fhb, N, 64, 1);
  k_head<<<nwb, 256, 0, stream>>>(fhb, Wf2, bf2, (float*)d_out, N);
}

// Round 5
// 825.484 us; speedup vs baseline: 2.2964x; 1.0757x over previous
//
#include <hip/hip_runtime.h>
#include <math.h>

// ---------------------------------------------------------------------------
// FraudGCN round 4: merged 3-output GEMM1, BN+ELU fused into GAT2 GEMM,
// s2 eliminated via weight composition, head fused into final GEMM,
// full-lane (edge,head) GAT stats.
// ---------------------------------------------------------------------------

typedef unsigned short u16;
typedef u16 us4 __attribute__((ext_vector_type(4)));
typedef short s8v __attribute__((ext_vector_type(8)));
typedef float f4v __attribute__((ext_vector_type(4)));

__device__ __forceinline__ float b2f(u16 u) {
  union { unsigned int i; float f; } v; v.i = ((unsigned int)u) << 16; return v.f;
}
__device__ __forceinline__ u16 f2b(float f) {
  union { float f; unsigned int i; } v; v.f = f;
  unsigned int u = v.i;
  return (u16)((u + 0x7fffu + ((u >> 16) & 1u)) >> 16);
}

// ---------------- casts ----------------
__global__ __launch_bounds__(256) void k_cast(const float* __restrict__ s, u16* __restrict__ d, int n4) {
  int i = blockIdx.x * blockDim.x + threadIdx.x;
  if (i < n4) {
    float4 v = *(reinterpret_cast<const float4*>(s) + i);
    us4 o = { f2b(v.x), f2b(v.y), f2b(v.z), f2b(v.w) };
    *(reinterpret_cast<us4*>(d) + i) = o;
  }
}

struct WcastDesc { const float* W; u16* Wt; int K; int M; };
struct WcastAll { WcastDesc d[5]; };
__global__ __launch_bounds__(256) void k_wcast_all(WcastAll a) {
  WcastDesc de = a.d[blockIdx.y];
  int n = de.K * de.M;
  int idx = blockIdx.x * blockDim.x + threadIdx.x;
  if (idx >= n) return;
  int c = idx / de.K, k = idx - c * de.K;
  de.Wt[idx] = f2b(de.W[(size_t)k * de.M + c]);
}

// Wc1t = (Wl2 @ Wf1b)^T, Wc2t = (Wr2 @ Wf1b)^T, biasC = bf1 + bl2 @ Wf1b
__global__ __launch_bounds__(256) void k_combine(const float* __restrict__ Wl2, const float* __restrict__ Wr2,
                                                 const float* __restrict__ bl2, const float* __restrict__ Wf1,
                                                 const float* __restrict__ bf1, u16* __restrict__ Wc1t,
                                                 u16* __restrict__ Wc2t, float* __restrict__ biasC) {
  int idx = blockIdx.x * 256 + threadIdx.x;
  if (idx >= 4096) return;
  int m = idx >> 6, k = idx & 63;
  float s1 = 0.f, s2 = 0.f;
  for (int j = 0; j < 64; ++j) {
    float wf = Wf1[(size_t)(64 + j) * 64 + m];
    s1 += Wl2[k * 64 + j] * wf;
    s2 += Wr2[k * 64 + j] * wf;
  }
  Wc1t[m * 64 + k] = f2b(s1);
  Wc2t[m * 64 + k] = f2b(s2);
  if (k == 0) {
    float b = bf1[m];
    for (int j = 0; j < 64; ++j) b += bl2[j] * Wf1[(size_t)(64 + j) * 64 + m];
    biasC[m] = b;
  }
}

// ---------------- CSR build ----------------
__global__ __launch_bounds__(256) void k_deg(const int* __restrict__ ei, int* __restrict__ deg, int E) {
  int e = blockIdx.x * blockDim.x + threadIdx.x;
  if (e < E) atomicAdd(&deg[ei[E + e]], 1);
}

__global__ __launch_bounds__(256) void k_scan1(const int* __restrict__ deg, int* __restrict__ row_ptr,
                                               int* __restrict__ bsum, int n) {
  __shared__ int sh[256];
  int tid = threadIdx.x;
  int i = blockIdx.x * 256 + tid;
  int v = (i < n) ? deg[i] : 0;
  sh[tid] = v;
  __syncthreads();
  for (int off = 1; off < 256; off <<= 1) {
    int t = (tid >= off) ? sh[tid - off] : 0;
    __syncthreads();
    sh[tid] += t;
    __syncthreads();
  }
  if (i < n) row_ptr[i] = sh[tid] - v;
  if (tid == 255) bsum[blockIdx.x] = sh[255];
}

__global__ __launch_bounds__(1024) void k_scan2(int* __restrict__ bsum, int* __restrict__ total, int nb) {
  __shared__ int sh[1024];
  int tid = threadIdx.x;
  int v = (tid < nb) ? bsum[tid] : 0;
  sh[tid] = v;
  __syncthreads();
  for (int off = 1; off < 1024; off <<= 1) {
    int t = (tid >= off) ? sh[tid - off] : 0;
    __syncthreads();
    sh[tid] += t;
    __syncthreads();
  }
  if (tid < nb) bsum[tid] = sh[tid] - v;
  if (tid == 1023) *total = sh[1023];
}

__global__ __launch_bounds__(256) void k_scan3(int* __restrict__ row_ptr, const int* __restrict__ bsum, int n) {
  int i = blockIdx.x * 256 + threadIdx.x;
  if (i < n) row_ptr[i] += bsum[blockIdx.x];
}

__global__ __launch_bounds__(256) void k_scatter(const int* __restrict__ ei, const int* __restrict__ row_ptr,
                                                 int* __restrict__ cursor, int* __restrict__ csr_src, int E) {
  int e = blockIdx.x * blockDim.x + threadIdx.x;
  if (e < E) {
    int d = ei[E + e];
    int pos = row_ptr[d] + atomicAdd(&cursor[d], 1);
    csr_src[pos] = ei[e];
  }
}

// ---------------- merged multi-output MFMA GEMM (shared A) ----------------
struct GemmSeg { const u16* Wt; u16* out; int ldout; const float* bias; };
struct Segs6 { GemmSeg s[6]; };
__global__ __launch_bounds__(256) void k_gemm_multi(const u16* __restrict__ A, int K, Segs6 sg, int Nrows) {
  GemmSeg seg = sg.s[blockIdx.y];
  __shared__ u16 As[64][40];
  __shared__ u16 Bs[64][40];
  int row0 = blockIdx.x * 64;
  int tid = threadIdx.x;
  int w = tid >> 6, lane = tid & 63;
  int lr = tid >> 2;
  int lseg = (tid & 3) * 8;
  f4v acc[4];
#pragma unroll
  for (int n = 0; n < 4; ++n) acc[n] = (f4v){0.f, 0.f, 0.f, 0.f};
  int ar = (w << 4) + (lane & 15);
  int ak = (lane >> 4) << 3;

  for (int k0 = 0; k0 < K; k0 += 32) {
    __syncthreads();
    int gr = row0 + lr;
    s8v av = {};
    if (gr < Nrows) av = *reinterpret_cast<const s8v*>(A + (size_t)gr * K + k0 + lseg);
    *reinterpret_cast<s8v*>(&As[lr][lseg]) = av;
    s8v bv = *reinterpret_cast<const s8v*>(seg.Wt + (size_t)lr * K + k0 + lseg);
    *reinterpret_cast<s8v*>(&Bs[lr][lseg]) = bv;
    __syncthreads();
    s8v af = *reinterpret_cast<const s8v*>(&As[ar][ak]);
#pragma unroll
    for (int n = 0; n < 4; ++n) {
      s8v bf = *reinterpret_cast<const s8v*>(&Bs[(n << 4) + (lane & 15)][ak]);
      acc[n] = __builtin_amdgcn_mfma_f32_16x16x32_bf16(af, bf, acc[n], 0, 0, 0);
    }
  }
  int r0 = row0 + (w << 4) + ((lane >> 4) << 2);
  int cc = lane & 15;
#pragma unroll
  for (int n = 0; n < 4; ++n) {
    int gc = (n << 4) + cc;
    float bv = seg.bias ? seg.bias[gc] : 0.f;
#pragma unroll
    for (int j = 0; j < 4; ++j) {
      int gr = r0 + j;
      if (gr < Nrows) seg.out[(size_t)gr * seg.ldout + gc] = f2b(acc[n][j] + bv);
    }
  }
}

// ---------------- GAT2 GEMM with BN+ELU fused on A-load ----------------
__global__ __launch_bounds__(256) void k_gemm_bn(const u16* __restrict__ A, int K, const u16* __restrict__ Wt,
                                                 const float* __restrict__ sc, const float* __restrict__ sh,
                                                 u16* __restrict__ C, int Nrows, int M) {
  __shared__ u16 As[64][40];
  __shared__ u16 Bs[64][40];
  int row0 = blockIdx.x * 64;
  int tid = threadIdx.x;
  int w = tid >> 6, lane = tid & 63;
  int lr = tid >> 2;
  int lseg = (tid & 3) * 8;
  f4v acc[4];
#pragma unroll
  for (int n = 0; n < 4; ++n) acc[n] = (f4v){0.f, 0.f, 0.f, 0.f};
  int ar = (w << 4) + (lane & 15);
  int ak = (lane >> 4) << 3;

  for (int k0 = 0; k0 < K; k0 += 32) {
    __syncthreads();
    int gr = row0 + lr;
    s8v av = {};
    if (gr < Nrows) {
      av = *reinterpret_cast<const s8v*>(A + (size_t)gr * K + k0 + lseg);
#pragma unroll
      for (int j = 0; j < 8; ++j) {
        int c = k0 + lseg + j;
        float a = b2f((u16)av[j]) * sc[c] + sh[c];
        a = (a > 0.f) ? a : (__expf(a) - 1.f);
        av[j] = (short)f2b(a);
      }
    }
    *reinterpret_cast<s8v*>(&As[lr][lseg]) = av;
    s8v bv = *reinterpret_cast<const s8v*>(Wt + (size_t)lr * K + k0 + lseg);
    *reinterpret_cast<s8v*>(&Bs[lr][lseg]) = bv;
    __syncthreads();
    s8v af = *reinterpret_cast<const s8v*>(&As[ar][ak]);
#pragma unroll
    for (int n = 0; n < 4; ++n) {
      s8v bf = *reinterpret_cast<const s8v*>(&Bs[(n << 4) + (lane & 15)][ak]);
      acc[n] = __builtin_amdgcn_mfma_f32_16x16x32_bf16(af, bf, acc[n], 0, 0, 0);
    }
  }
  int r0 = row0 + (w << 4) + ((lane >> 4) << 2);
  int cc = lane & 15;
#pragma unroll
  for (int n = 0; n < 4; ++n) {
    int gc = (n << 4) + cc;
#pragma unroll
    for (int j = 0; j < 4; ++j) {
      int gr = r0 + j;
      if (gr < Nrows) C[(size_t)gr * M + gc] = f2b(acc[n][j]);
    }
  }
}

// ---------------- final GEMM: 3 inputs + fused head -> logits ----------------
__global__ __launch_bounds__(256) void k_gemm_final(const u16* __restrict__ A1, const u16* __restrict__ W1,
                                                    const u16* __restrict__ A2, const u16* __restrict__ W2,
                                                    const u16* __restrict__ A3, const u16* __restrict__ W3,
                                                    const float* __restrict__ biasC, const float* __restrict__ Wf2,
                                                    const float* __restrict__ bf2, float* __restrict__ out,
                                                    int Nrows) {
  __shared__ u16 As[64][40];
  __shared__ u16 Bs[64][40];
  int row0 = blockIdx.x * 64;
  int tid = threadIdx.x;
  int w = tid >> 6, lane = tid & 63;
  int lr = tid >> 2;
  int lseg = (tid & 3) * 8;
  f4v acc[4];
#pragma unroll
  for (int n = 0; n < 4; ++n) acc[n] = (f4v){0.f, 0.f, 0.f, 0.f};
  int ar = (w << 4) + (lane & 15);
  int ak = (lane >> 4) << 3;

  const u16* Aarr[3] = {A1, A2, A3};
  const u16* Warr[3] = {W1, W2, W3};
#pragma unroll
  for (int ph = 0; ph < 3; ++ph) {
    const u16* A = Aarr[ph];
    const u16* Wt = Warr[ph];
#pragma unroll
    for (int k0 = 0; k0 < 64; k0 += 32) {
      __syncthreads();
      int gr = row0 + lr;
      s8v av = {};
      if (gr < Nrows) av = *reinterpret_cast<const s8v*>(A + (size_t)gr * 64 + k0 + lseg);
      *reinterpret_cast<s8v*>(&As[lr][lseg]) = av;
      s8v bv = *reinterpret_cast<const s8v*>(Wt + (size_t)lr * 64 + k0 + lseg);
      *reinterpret_cast<s8v*>(&Bs[lr][lseg]) = bv;
      __syncthreads();
      s8v af = *reinterpret_cast<const s8v*>(&As[ar][ak]);
#pragma unroll
      for (int n = 0; n < 4; ++n) {
        s8v bf = *reinterpret_cast<const s8v*>(&Bs[(n << 4) + (lane & 15)][ak]);
        acc[n] = __builtin_amdgcn_mfma_f32_16x16x32_bf16(af, bf, acc[n], 0, 0, 0);
      }
    }
  }

  // fused head: out[r,0:2] = relu(fh) @ Wf2 + bf2
  int r0 = row0 + (w << 4) + ((lane >> 4) << 2);
  int cc = lane & 15;
  float p0[4] = {0.f, 0.f, 0.f, 0.f}, p1[4] = {0.f, 0.f, 0.f, 0.f};
#pragma unroll
  for (int n = 0; n < 4; ++n) {
    int col = (n << 4) + cc;
    float bC = biasC[col];
    float w0 = Wf2[col * 2 + 0], w1 = Wf2[col * 2 + 1];
#pragma unroll
    for (int j = 0; j < 4; ++j) {
      float f = fmaxf(acc[n][j] + bC, 0.f);
      p0[j] += f * w0;
      p1[j] += f * w1;
    }
  }
#pragma unroll
  for (int off = 1; off < 16; off <<= 1) {
#pragma unroll
    for (int j = 0; j < 4; ++j) {
      p0[j] += __shfl_xor(p0[j], off, 64);
      p1[j] += __shfl_xor(p1[j], off, 64);
    }
  }
  if (cc == 0) {
    float b0 = bf2[0], b1 = bf2[1];
#pragma unroll
    for (int j = 0; j < 4; ++j) {
      int gr = r0 + j;
      if (gr < Nrows) {
        out[(size_t)gr * 2 + 0] = p0[j] + b0;
        out[(size_t)gr * 2 + 1] = p1[j] + b1;
      }
    }
  }
}

// ---------------- GAT attention prep (bf16 h) ----------------
template <int H, int C>
__global__ __launch_bounds__(256) void k_attn_prep(const u16* __restrict__ h, const float* __restrict__ a_src,
                                                   const float* __restrict__ a_dst, float* __restrict__ e_src,
                                                   float* __restrict__ e_dst, int n) {
  constexpr int HC = H * C;
  constexpr int VW = HC / 64;
  constexpr int GROUP = C / VW;
  int wid = (blockIdx.x * blockDim.x + threadIdx.x) >> 6;
  int lane = threadIdx.x & 63;
  if (wid >= n) return;
  int c0 = lane * VW;
  float ps = 0.f, pd = 0.f;
  if constexpr (VW == 4) {
    us4 v = *reinterpret_cast<const us4*>(h + (size_t)wid * HC + c0);
#pragma unroll
    for (int j = 0; j < 4; ++j) {
      float hv = b2f(v[j]);
      ps += hv * a_src[c0 + j];
      pd += hv * a_dst[c0 + j];
    }
  } else {
    float hv = b2f(h[(size_t)wid * HC + c0]);
    ps = hv * a_src[c0];
    pd = hv * a_dst[c0];
  }
#pragma unroll
  for (int off = 1; off < GROUP; off <<= 1) {
    ps += __shfl_xor(ps, off, 64);
    pd += __shfl_xor(pd, off, 64);
  }
  if ((lane & (GROUP - 1)) == 0) {
    int hh = c0 / C;
    e_src[(size_t)wid * H + hh] = ps;
    e_dst[(size_t)wid * H + hh] = pd;
  }
}

// ---------------- GAT stats H=4: (edge,head) lanes, full utilization --------
__global__ __launch_bounds__(256) void k_gat_stats4(const float* __restrict__ es, const float* __restrict__ ed,
                                                    const int* __restrict__ row_ptr, const int* __restrict__ csr,
                                                    float* __restrict__ alphaE, float* __restrict__ alphaS, int n) {
  int wid = (blockIdx.x * blockDim.x + threadIdx.x) >> 6;
  int lane = threadIdx.x & 63;
  if (wid >= n) return;
  int start = row_ptr[wid];
  int deg = row_ptr[wid + 1] - start;
  int h = lane & 3, esl = lane >> 2;  // head, edge-slot 0..15
  float edst = ed[(size_t)wid * 4 + h];

  float m = -1e30f, s = 0.f;
  for (int e = esl; e < deg + 1; e += 16) {
    int sn = (e < deg) ? csr[start + e] : wid;
    float v = es[(size_t)sn * 4 + h] + edst;
    v = (v >= 0.f) ? v : 0.2f * v;
    if (v > m) {
      s = s * __expf(m - v) + 1.f;
      m = v;
    } else {
      s += __expf(v - m);
    }
  }
#pragma unroll
  for (int off = 4; off < 64; off <<= 1) {
    float mo = __shfl_xor(m, off, 64);
    float so = __shfl_xor(s, off, 64);
    float M = fmaxf(m, mo);
    s = s * __expf(m - M) + so * __expf(mo - M);
    m = M;
  }
  float invS = 1.f / s;
  for (int e = esl; e < deg + 1; e += 16) {
    int sn = (e < deg) ? csr[start + e] : wid;
    float v = es[(size_t)sn * 4 + h] + edst;
    v = (v >= 0.f) ? v : 0.2f * v;
    float a = __expf(v - m) * invS;
    if (e < deg) alphaE[(size_t)(start + e) * 4 + h] = a;
    else alphaS[(size_t)wid * 4 + h] = a;
  }
}

// ---------------- GAT stats H=1 (lane per edge) ----------------
__global__ __launch_bounds__(256) void k_gat_stats1(const float* __restrict__ es, const float* __restrict__ ed,
                                                    const int* __restrict__ row_ptr, const int* __restrict__ csr,
                                                    float* __restrict__ alphaE, float* __restrict__ alphaS, int n) {
  int wid = (blockIdx.x * blockDim.x + threadIdx.x) >> 6;
  int lane = threadIdx.x & 63;
  if (wid >= n) return;
  int start = row_ptr[wid];
  int deg = row_ptr[wid + 1] - start;
  float edst = ed[wid];
  float m = -1e30f, s = 0.f;
  for (int e = lane; e < deg + 1; e += 64) {
    int sn = (e < deg) ? csr[start + e] : wid;
    float v = es[sn] + edst;
    v = (v >= 0.f) ? v : 0.2f * v;
    if (v > m) {
      s = s * __expf(m - v) + 1.f;
      m = v;
    } else {
      s += __expf(v - m);
    }
  }
#pragma unroll
  for (int off = 1; off < 64; off <<= 1) {
    float mo = __shfl_xor(m, off, 64);
    float so = __shfl_xor(s, off, 64);
    float M = fmaxf(m, mo);
    s = s * __expf(m - M) + so * __expf(mo - M);
    m = M;
  }
  float invS = 1.f / s;
  for (int e = lane; e < deg + 1; e += 64) {
    int sn = (e < deg) ? csr[start + e] : wid;
    float v = es[sn] + edst;
    v = (v >= 0.f) ? v : 0.2f * v;
    float a = __expf(v - m) * invS;
    if (e < deg) alphaE[start + e] = a;
    else alphaS[wid] = a;
  }
}

// ---------------- GAT aggregate pass 2 (precomputed alphas) ----------------
template <int H, int C>
__global__ __launch_bounds__(256) void k_gat_agg2(const u16* __restrict__ h, const float* __restrict__ alphaE,
                                                  const float* __restrict__ alphaS, const int* __restrict__ row_ptr,
                                                  const int* __restrict__ csr, const float* __restrict__ bias,
                                                  u16* __restrict__ out, int n) {
  constexpr int HC = H * C;
  constexpr int VW = HC / 64;
  int wid = (blockIdx.x * blockDim.x + threadIdx.x) >> 6;
  int lane = threadIdx.x & 63;
  if (wid >= n) return;
  int start = row_ptr[wid];
  int deg = row_ptr[wid + 1] - start;
  int hl = (lane * VW) / C;

  float acc[VW];
  {
    float aS = alphaS[(size_t)wid * H + hl];
    if constexpr (VW == 4) {
      us4 hv = *(reinterpret_cast<const us4*>(h + (size_t)wid * HC) + lane);
#pragma unroll
      for (int j = 0; j < 4; ++j) acc[j] = aS * b2f(hv[j]);
    } else {
      acc[0] = aS * b2f(h[(size_t)wid * HC + lane]);
    }
  }

  int e = 0;
  for (; e + 4 <= deg; e += 4) {
    int sn[4];
    float al[4];
#pragma unroll
    for (int i = 0; i < 4; ++i) {
      sn[i] = csr[start + e + i];
      al[i] = alphaE[(size_t)(start + e + i) * H + hl];
    }
#pragma unroll
    for (int i = 0; i < 4; ++i) {
      if constexpr (VW == 4) {
        us4 hv = *(reinterpret_cast<const us4*>(h + (size_t)sn[i] * HC) + lane);
#pragma unroll
        for (int j = 0; j < 4; ++j) acc[j] += al[i] * b2f(hv[j]);
      } else {
        acc[0] += al[i] * b2f(h[(size_t)sn[i] * HC + lane]);
      }
    }
  }
  for (; e < deg; ++e) {
    int sn = csr[start + e];
    float al = alphaE[(size_t)(start + e) * H + hl];
    if constexpr (VW == 4) {
      us4 hv = *(reinterpret_cast<const us4*>(h + (size_t)sn * HC) + lane);
#pragma unroll
      for (int j = 0; j < 4; ++j) acc[j] += al * b2f(hv[j]);
    } else {
      acc[0] += al * b2f(h[(size_t)sn * HC + lane]);
    }
  }

  int c0 = lane * VW;
#pragma unroll
  for (int j = 0; j < VW; ++j) out[(size_t)wid * HC + c0 + j] = f2b(acc[j] + bias[c0 + j]);
}

// ---------------- SAGE mean aggregation, optional Cin add ----------------
__global__ __launch_bounds__(256) void k_sage_agg64(const u16* __restrict__ x, const int* __restrict__ row_ptr,
                                                    const int* __restrict__ csr, const u16* __restrict__ Cin,
                                                    u16* __restrict__ agg, int n) {
  int wid = (blockIdx.x * blockDim.x + threadIdx.x) >> 6;
  int lane = threadIdx.x & 63;
  if (wid >= n) return;
  int start = row_ptr[wid];
  int deg = row_ptr[wid + 1] - start;
  float acc = 0.f;
  int e = 0;
  for (; e + 4 <= deg; e += 4) {
    int sn[4];
#pragma unroll
    for (int i = 0; i < 4; ++i) sn[i] = csr[start + e + i];
#pragma unroll
    for (int i = 0; i < 4; ++i) acc += b2f(x[(size_t)sn[i] * 64 + lane]);
  }
  for (; e < deg; ++e) acc += b2f(x[(size_t)csr[start + e] * 64 + lane]);
  float inv = 1.f / fmaxf((float)deg, 1.f);
  float base = Cin ? b2f(Cin[(size_t)wid * 64 + lane]) : 0.f;
  agg[(size_t)wid * 64 + lane] = f2b(acc * inv + base);
}

// ---------------- BatchNorm ----------------
template <int CH>
__global__ __launch_bounds__(256) void k_bn_stats(const u16* __restrict__ x, float* __restrict__ stats, int n) {
  constexpr int RPB = 256 / CH;
  int tid = threadIdx.x;
  int c = tid % CH;
  int rsub = tid / CH;
  float s = 0.f, q = 0.f;
  for (int r = blockIdx.x * RPB + rsub; r < n; r += gridDim.x * RPB) {
    float v = b2f(x[(size_t)r * CH + c]);
    s += v;
    q += v * v;
  }
  __shared__ float ls[256], lq[256];
  ls[tid] = s; lq[tid] = q;
  __syncthreads();
  if (tid < CH) {
#pragma unroll
    for (int i = 1; i < RPB; ++i) { s += ls[tid + i * CH]; q += lq[tid + i * CH]; }
    atomicAdd(&stats[c], s);
    atomicAdd(&stats[CH + c], q);
  }
}

template <int CH>
__global__ __launch_bounds__(256) void k_bn_final(const float* __restrict__ stats, const float* __restrict__ gamma,
                                                  const float* __restrict__ beta, float* __restrict__ sc,
                                                  float* __restrict__ sh, int n) {
  int c = threadIdx.x;
  if (c >= CH) return;
  float invn = 1.f / (float)n;
  float mu = stats[c] * invn;
  float var = stats[CH + c] * invn - mu * mu;
  float rs = rsqrtf(var + 1e-5f);
  sc[c] = rs * gamma[c];
  sh[c] = beta[c] - mu * rs * gamma[c];
}

template <int CH>
__global__ __launch_bounds__(256) void k_bn_apply(u16* __restrict__ x, const float* __restrict__ stats,
                                                  const float* __restrict__ gamma, const float* __restrict__ beta,
                                                  int n, int act) {
  float invn = 1.f / (float)n;
  size_t total = (size_t)n * CH;
  for (size_t idx = (size_t)blockIdx.x * blockDim.x + threadIdx.x; idx < total;
       idx += (size_t)gridDim.x * blockDim.x) {
    int c = (int)(idx % CH);
    float mu = stats[c] * invn;
    float var = stats[CH + c] * invn - mu * mu;
    float v = (b2f(x[idx]) - mu) * rsqrtf(var + 1e-5f) * gamma[c] + beta[c];
    if (act == 1) v = fmaxf(v, 0.f);
    else v = (v > 0.f) ? v : (__expf(v) - 1.f);
    x[idx] = f2b(v);
  }
}

// ---------------------------------------------------------------------------
extern "C" void kernel_launch(void* const* d_in, const int* in_sizes, int n_in,
                              void* d_out, int out_size, void* d_ws, size_t ws_size,
                              hipStream_t stream) {
  const float* x      = (const float*)d_in[0];
  const int*   ei     = (const int*)d_in[1];
  const float* W1g    = (const float*)d_in[2];
  const float* a_src1 = (const float*)d_in[3];
  const float* a_dst1 = (const float*)d_in[4];
  const float* b1g    = (const float*)d_in[5];
  const float* bn1g_g = (const float*)d_in[6];
  const float* bn1g_b = (const float*)d_in[7];
  const float* W2g    = (const float*)d_in[8];
  const float* a_src2 = (const float*)d_in[9];
  const float* a_dst2 = (const float*)d_in[10];
  const float* b2g    = (const float*)d_in[11];
  const float* Wl1    = (const float*)d_in[12];
  const float* bl1    = (const float*)d_in[13];
  const float* Wr1    = (const float*)d_in[14];
  const float* bn1s_g = (const float*)d_in[15];
  const float* bn1s_b = (const float*)d_in[16];
  const float* Wl2    = (const float*)d_in[17];
  const float* bl2    = (const float*)d_in[18];
  const float* Wr2    = (const float*)d_in[19];
  const float* Wf1    = (const float*)d_in[20];
  const float* bf1    = (const float*)d_in[21];
  const float* Wf2    = (const float*)d_in[22];
  const float* bf2    = (const float*)d_in[23];

  const int N = in_sizes[0] / 128;  // 100000
  const int E = in_sizes[1] / 2;    // 1600000

  char* ws = (char*)d_ws;
  size_t off = 0;
  auto alloc = [&](size_t bytes) -> void* {
    size_t o = (off + 255) & ~(size_t)255;
    off = o + bytes;
    return (void*)(ws + o);
  };

  u16* xb    = (u16*)alloc((size_t)N * 128 * 2);
  u16* h1b   = (u16*)alloc((size_t)N * 256 * 2);   // sagg2b overlays after GAT1 agg
  u16* gb    = (u16*)alloc((size_t)N * 256 * 2);
  u16* h2b   = (u16*)alloc((size_t)N * 64 * 2);
  u16* g2b   = (u16*)alloc((size_t)N * 64 * 2);
  u16* xlb   = (u16*)alloc((size_t)N * 64 * 2);
  u16* xrb   = (u16*)alloc((size_t)N * 64 * 2);
  u16* s1b   = (u16*)alloc((size_t)N * 64 * 2);
  float* es1 = (float*)alloc((size_t)N * 4 * 4);
  float* ed1 = (float*)alloc((size_t)N * 4 * 4);
  float* es2 = (float*)alloc((size_t)N * 4);
  float* ed2 = (float*)alloc((size_t)N * 4);
  float* alphaE = (float*)alloc((size_t)E * 4 * 4);
  float* alphaS = (float*)alloc((size_t)N * 4 * 4);
  int* deg     = (int*)alloc((size_t)N * 2 * 4);   // deg + cursor contiguous
  int* cursor  = deg + N;
  int* row_ptr = (int*)alloc((size_t)(N + 1) * 4);
  int* bsum    = (int*)alloc(1024 * 4);
  int* csr     = (int*)alloc((size_t)E * 4);
  float* statsG = (float*)alloc((512 + 128) * 4);  // 2*256 gb stats + 2*64 s1 stats
  float* statsS = statsG + 512;
  float* scg   = (float*)alloc(256 * 4);
  float* shg   = (float*)alloc(256 * 4);
  float* biasC = (float*)alloc(64 * 4);
  u16* W1t  = (u16*)alloc(256 * 128 * 2);
  u16* W2t  = (u16*)alloc(64 * 256 * 2);
  u16* Wl1t = (u16*)alloc(64 * 128 * 2);
  u16* Wr1t = (u16*)alloc(64 * 128 * 2);
  u16* Wf1at= (u16*)alloc(64 * 64 * 2);
  u16* Wc1t = (u16*)alloc(64 * 64 * 2);
  u16* Wc2t = (u16*)alloc(64 * 64 * 2);
  // overlay: sagg2 over h1b (h1b dead after GAT1 aggregation)
  u16* sagg2b = h1b;

  const int tb = 256;
  const int nwb = (N + 3) / 4;
  const int nsb = (N + 255) / 256;

  // ---- CSR build + zeroing ----
  hipMemsetAsync(deg, 0, (size_t)N * 2 * 4, stream);
  hipMemsetAsync(statsG, 0, (512 + 128) * 4, stream);
  k_deg<<<(E + tb - 1) / tb, tb, 0, stream>>>(ei, deg, E);
  k_scan1<<<nsb, 256, 0, stream>>>(deg, row_ptr, bsum, N);
  k_scan2<<<1, 1024, 0, stream>>>(bsum, row_ptr + N, nsb);
  k_scan3<<<nsb, 256, 0, stream>>>(row_ptr, bsum, N);
  k_scatter<<<(E + tb - 1) / tb, tb, 0, stream>>>(ei, row_ptr, cursor, csr, E);

  // ---- casts / weight prep ----
  k_cast<<<((N * 128 / 4) + tb - 1) / tb, tb, 0, stream>>>(x, xb, N * 128 / 4);
  WcastAll wa;
  wa.d[0] = { W1g, W1t, 128, 256 };
  wa.d[1] = { W2g, W2t, 256, 64 };
  wa.d[2] = { Wl1, Wl1t, 128, 64 };
  wa.d[3] = { Wr1, Wr1t, 128, 64 };
  wa.d[4] = { Wf1, Wf1at, 64, 64 };
  dim3 wgrid((128 * 256 + tb - 1) / tb, 5);
  k_wcast_all<<<wgrid, tb, 0, stream>>>(wa);
  k_combine<<<16, 256, 0, stream>>>(Wl2, Wr2, bl2, Wf1, bf1, Wc1t, Wc2t, biasC);

  const int gx = (N + 63) / 64;

  // ---- merged GEMM: h1 (4 segs) | xl | xr+bl1 ----
  Segs6 sg;
  sg.s[0] = { W1t,            h1b,       256, nullptr };
  sg.s[1] = { W1t + 64 * 128, h1b + 64,  256, nullptr };
  sg.s[2] = { W1t + 128 * 128, h1b + 128, 256, nullptr };
  sg.s[3] = { W1t + 192 * 128, h1b + 192, 256, nullptr };
  sg.s[4] = { Wl1t,           xlb,       64,  nullptr };
  sg.s[5] = { Wr1t,           xrb,       64,  bl1 };
  k_gemm_multi<<<dim3(gx, 6), 256, 0, stream>>>(xb, 128, sg, N);

  // ---- GAT layer 1 ----
  k_attn_prep<4, 64><<<nwb, 256, 0, stream>>>(h1b, a_src1, a_dst1, es1, ed1, N);
  k_gat_stats4<<<nwb, 256, 0, stream>>>(es1, ed1, row_ptr, csr, alphaE, alphaS, N);
  k_gat_agg2<4, 64><<<nwb, 256, 0, stream>>>(h1b, alphaE, alphaS, row_ptr, csr, b1g, gb, N);
  k_bn_stats<256><<<256, 256, 0, stream>>>(gb, statsG, N);
  k_bn_final<256><<<1, 256, 0, stream>>>(statsG, bn1g_g, bn1g_b, scg, shg, N);

  // ---- SAGE layer 1: s1 = mean_agg(xl) + xr (xr already has bl1) ----
  k_sage_agg64<<<nwb, 256, 0, stream>>>(xlb, row_ptr, csr, xrb, s1b, N);
  k_bn_stats<64><<<256, 256, 0, stream>>>(s1b, statsS, N);
  k_bn_apply<64><<<2048, 256, 0, stream>>>(s1b, statsS, bn1s_g, bn1s_b, N, 1);

  // ---- GAT layer 2 (BN+ELU fused into GEMM A-load) ----
  k_gemm_bn<<<dim3(gx, 1), 256, 0, stream>>>(gb, 256, W2t, scg, shg, h2b, N, 64);
  k_attn_prep<1, 64><<<nwb, 256, 0, stream>>>(h2b, a_src2, a_dst2, es2, ed2, N);
  k_gat_stats1<<<nwb, 256, 0, stream>>>(es2, ed2, row_ptr, csr, alphaE, alphaS, N);
  k_gat_agg2<1, 64><<<nwb, 256, 0, stream>>>(h2b, alphaE, alphaS, row_ptr, csr, b2g, g2b, N);

  // ---- SAGE layer 2 aggregation ----
  k_sage_agg64<<<nwb, 256, 0, stream>>>(s1b, row_ptr, csr, nullptr, sagg2b, N);

  // ---- final: fh = relu(g2@Wf1a + sagg2@Wc1 + s1@Wc2 + biasC); out = fh@Wf2+bf2
  k_gemm_final<<<dim3(gx, 1), 256, 0, stream>>>(g2b, Wf1at, sagg2b, Wc1t, s1b, Wc2t,
                                                biasC, Wf2, bf2, (float*)d_out, N);
}